// Round 10
// baseline (535.182 us; speedup 1.0000x reference)
//
#include <hip/hip_runtime.h>
#include <hip/hip_bf16.h>
#include <stdint.h>

#define N_NODES 100000

typedef unsigned short us16;
typedef short bf16x8 __attribute__((ext_vector_type(8)));
typedef float f32x4 __attribute__((ext_vector_type(4)));

__device__ __forceinline__ float us2f(us16 u){
  union{ unsigned int i; float f; } x; x.i = ((unsigned int)u) << 16; return x.f;
}
__device__ __forceinline__ us16 f2us(float f){
  union{ float f; unsigned int i; } x; x.f = f;
  unsigned int i = x.i;
  unsigned int r = (i + 0x7FFFu + ((i >> 16) & 1u)) >> 16;
  return (us16)r;
}

// ---------------- init: zero cnt ----------------
__global__ __launch_bounds__(256) void k_init(int* __restrict__ cnt, int n2){
  int i = blockIdx.x*256 + threadIdx.x;
  if (i < n2) cnt[i]=0;
}

// ------- per-(type,dst) counts: ONE int atomic per edge; rank stored coalesced -------
__global__ __launch_bounds__(256) void k_cnt(const int* __restrict__ dst,
                                             const int* __restrict__ et,
                                             int* __restrict__ cnt,
                                             int* __restrict__ eofs, int E){
  int e = blockIdx.x*256 + threadIdx.x;
  if (e>=E) return;
  int d = dst[e]; int t = et[e];
  eofs[e] = atomicAdd(&cnt[t*N_NODES + d], 1);
}

// ---------------- exclusive scan over M elements (R1-exact) ----------------
__global__ __launch_bounds__(256) void k_scan_reduce(const int* __restrict__ in, int* __restrict__ bsum, int M){
  __shared__ int sd[256];
  int base = blockIdx.x*2048; int t = threadIdx.x;
  int sum = 0;
  #pragma unroll
  for(int i=0;i<8;i++){ int p = base + t*8 + i; if(p<M) sum += in[p]; }
  sd[t]=sum; __syncthreads();
  for(int s=128;s>0;s>>=1){ if(t<s) sd[t]+=sd[t+s]; __syncthreads(); }
  if(t==0) bsum[blockIdx.x]=sd[0];
}
__global__ void k_scan_top(int* __restrict__ bsum, int B){
  if (threadIdx.x==0){ int run=0; for(int i=0;i<B;i++){ int v=bsum[i]; bsum[i]=run; run+=v; } }
}
__global__ __launch_bounds__(256) void k_scan_apply(const int* __restrict__ in, const int* __restrict__ bsum,
                                                    int* __restrict__ out, int M){
  __shared__ int sd[256];
  int base = blockIdx.x*2048; int t = threadIdx.x;
  int loc[8]; int sum=0;
  #pragma unroll
  for(int i=0;i<8;i++){ int p = base + t*8 + i; int v = (p<M)?in[p]:0; loc[i]=sum; sum+=v; }
  sd[t]=sum; __syncthreads();
  for(int ofs=1;ofs<256;ofs<<=1){
    int v = (t>=ofs)? sd[t-ofs] : 0;
    __syncthreads();
    sd[t]+=v;
    __syncthreads();
  }
  int excl = ((t==0)?0:sd[t-1]) + bsum[blockIdx.x];
  #pragma unroll
  for(int i=0;i<8;i++){ int p = base + t*8 + i; if(p<M) out[p]=excl+loc[i]; }
}

// ---------------- CSR fill: NO atomic (pos = rp + precomputed rank) ----------------
__global__ __launch_bounds__(256) void k_edge_fill(const int* __restrict__ src, const int* __restrict__ dst,
  const int* __restrict__ et, const float* __restrict__ ew,
  const int* __restrict__ rp, const int* __restrict__ eofs,
  uint2* __restrict__ csr, int E){
  int e = blockIdx.x*256+threadIdx.x;
  if(e>=E) return;
  int s=src[e], d=dst[e], t=et[e]; float w=ew[e];
  int idx = t*N_NODES + d;
  int pos = rp[idx] + eofs[e];
  csr[pos] = make_uint2((unsigned)s, __float_as_uint(w));
}

// ---------------- degree from CSR (sequential, atomic-free) ----------------
__global__ __launch_bounds__(256) void k_deg_csr(const uint2* __restrict__ csr,
                                                 const int* __restrict__ rp, const int* __restrict__ cnt,
                                                 float* __restrict__ disA, int M){
  int i = blockIdx.x*256+threadIdx.x;
  if(i>=M) return;
  int e0 = rp[i], c = cnt[i];
  float s = 1.0f;
  for(int e=e0; e<e0+c; e++) s += __uint_as_float(csr[e].y);
  disA[i] = rsqrtf(s);
}

// ---------------- fold dis[src] into coefficients: coef = w * dis[s] ----------------
__global__ __launch_bounds__(256) void k_coef(uint2* __restrict__ csr,
                                              const int* __restrict__ rp,
                                              const float* __restrict__ disA, int E){
  int e = blockIdx.x*256+threadIdx.x;
  if(e>=E) return;
  int rpN = rp[N_NODES];               // boundary: first type-1 entry
  int t = (e >= rpN) ? 1 : 0;
  uint2 q = csr[e];
  float w = __uint_as_float(q.y) * disA[t*N_NODES + (int)q.x];
  csr[e] = make_uint2(q.x, __float_as_uint(w));
}

// ---------------- weight prep: f32 [K][NC] -> bf16 transposed [NC][K] ----------------
__global__ __launch_bounds__(256) void k_prepw(const float* __restrict__ ft_w,
                                               const float* __restrict__ g0_w, const float* __restrict__ g1_w,
                                               const float* __restrict__ p_w1, const float* __restrict__ p_w2,
                                               us16* __restrict__ wt){
  int m = blockIdx.y;
  const float* srcp; int K, NCc; us16* dstp;
  switch(m){
    case 0: srcp=ft_w;        K=128; NCc=128; dstp=wt;        break;
    case 1: srcp=g0_w;        K=128; NCc=128; dstp=wt+16384;  break;
    case 2: srcp=g0_w+16384;  K=128; NCc=128; dstp=wt+32768;  break;
    case 3: srcp=g1_w;        K=128; NCc=128; dstp=wt+49152;  break;
    case 4: srcp=g1_w+16384;  K=128; NCc=128; dstp=wt+65536;  break;
    case 5: srcp=p_w1;        K=256; NCc=64;  dstp=wt+81920;  break;
    default:srcp=p_w2;        K=64;  NCc=64;  dstp=wt+98304;  break;
  }
  int idx = blockIdx.x*256+threadIdx.x;
  if(idx >= K*NCc) return;
  int nn = idx / K, k = idx - nn*K;
  dstp[idx] = f2us(srcp[(size_t)k*NCc + nn]);
}

// ---------- MFMA GEMM (R6-verified core): C[n,NC](bf16) = A@W (+bias/addv, relu) ----------
template<int NC, typename AT>
__global__ __launch_bounds__(256) void k_mgemm(const AT* __restrict__ A0, const AT* __restrict__ A1,
                 int lda, const us16* __restrict__ Wt,
                 const float* __restrict__ bias, const float* __restrict__ addv,
                 us16* __restrict__ C, int ldc, int n, int KC, int relu){
  constexpr int NB = NC/16;
  __shared__ us16 Alds[128*64];
  __shared__ us16 Wlds[NC*64];
  const int tid = threadIdx.x;
  const int lane = tid & 63, wid = tid >> 6;
  const int rowBase = blockIdx.x*128;
  f32x4 zero = {0.f,0.f,0.f,0.f};
  f32x4 acc[2][NB];
  #pragma unroll
  for(int m=0;m<2;m++)
    #pragma unroll
    for(int nb=0;nb<NB;nb++) acc[m][nb] = zero;

  for(int kk=0; kk<KC; kk+=64){
    const AT* Ab = (kk<128)? A0 : A1;
    const int kc = (kk<128)? kk : (kk-128);
    #pragma unroll
    for(int p=0;p<4;p++){
      int idx = p*256 + tid;
      int r = idx>>3, u = idx&7;
      int row = rowBase + r;
      uint4 v = make_uint4(0u,0u,0u,0u);
      if(row<n){
        if constexpr (sizeof(AT)==2){
          v = *(const uint4*)(Ab + (size_t)row*lda + kc + u*8);
        } else {
          float4 f0 = *(const float4*)(Ab + (size_t)row*lda + kc + u*8);
          float4 f1 = *(const float4*)(Ab + (size_t)row*lda + kc + u*8 + 4);
          us16 tmp[8] = {f2us(f0.x),f2us(f0.y),f2us(f0.z),f2us(f0.w),
                         f2us(f1.x),f2us(f1.y),f2us(f1.z),f2us(f1.w)};
          v = *(const uint4*)tmp;
        }
      }
      *(uint4*)&Alds[(r*8 + (u ^ (r&7)))*8] = v;
    }
    #pragma unroll
    for(int p=0;p<NB/2;p++){
      int idx = p*256 + tid;
      int cI = idx>>3, u = idx&7;
      uint4 v = *(const uint4*)(Wt + (size_t)cI*KC + kk + u*8);
      *(uint4*)&Wlds[(cI*8 + (u ^ (cI&7)))*8] = v;
    }
    __syncthreads();
    #pragma unroll
    for(int ks=0;ks<2;ks++){
      bf16x8 af[2];
      #pragma unroll
      for(int m=0;m<2;m++){
        int r = wid*32 + m*16 + (lane&15);
        int u = (ks*4 + (lane>>4)) ^ (r&7);
        af[m] = *(const bf16x8*)&Alds[(r*8+u)*8];
      }
      #pragma unroll
      for(int nb=0;nb<NB;nb++){
        int c2 = nb*16 + (lane&15);
        int u = (ks*4 + (lane>>4)) ^ (c2&7);
        bf16x8 bfv = *(const bf16x8*)&Wlds[(c2*8+u)*8];
        #pragma unroll
        for(int m=0;m<2;m++)
          acc[m][nb] = __builtin_amdgcn_mfma_f32_16x16x32_bf16(af[m], bfv, acc[m][nb], 0,0,0);
      }
    }
    __syncthreads();
  }
  #pragma unroll
  for(int nb=0;nb<NB;nb++){
    int col = nb*16 + (lane&15);
    float badd = (bias? bias[col]:0.f) + (addv? addv[col]:0.f);
    #pragma unroll
    for(int m=0;m<2;m++){
      #pragma unroll
      for(int j=0;j<4;j++){
        int row = rowBase + wid*32 + m*16 + (lane>>4)*4 + j;
        if(row<n){
          float v = acc[m][nb][j] + badd;
          if(relu) v = fmaxf(v,0.f);
          C[(size_t)row*ldc + col] = f2us(v);
        }
      }
    }
  }
}

// ------------- aggregation: 4 edge-groups x 16 lanes, dwordx4 gathers, 8 edges in flight -------------
// Wave = 1 dst row. Group g (lanes 16g..16g+15) processes edges it*8+g and it*8+4+g.
// Lane slot k (lane&15) covers cols [k*8, k*8+8) (16B). Cross-group shfl_xor reduce; group 0 epilogue.
__global__ __launch_bounds__(256) void k_agg(const us16* __restrict__ T,
  const uint2* __restrict__ csr,
  const int* __restrict__ rp, const int* __restrict__ cnt, int rowOfs,
  const float* __restrict__ dis,
  const float* __restrict__ bias, const float* __restrict__ gamma, const float* __restrict__ beta,
  const float* __restrict__ rm, const float* __restrict__ rv,
  const us16* __restrict__ resid,
  us16* __restrict__ out, int relu, int n){
  const int wid = threadIdx.x >> 6, lane = threadIdx.x & 63;
  const int g = lane >> 4;      // edge group 0..3
  const int k = lane & 15;      // 16B slot in row
  int r = blockIdx.x*4 + wid;
  if (r >= n) return;
  int idx = rowOfs + r;
  int e0 = rp[idx];
  int ec = cnt[idx];
  const uint2* cp = csr + e0;
  const int c0 = k*8;
  float acc[8];
  #pragma unroll
  for(int j=0;j<8;j++) acc[j]=0.f;

  int nit = (ec + 7) >> 3;
  for(int it=0; it<nit; it++){
    int eA = it*8 + g;
    int eB = it*8 + 4 + g;
    uint2 qA = (eA<ec)? cp[eA] : make_uint2(0u,0u);
    uint2 qB = (eB<ec)? cp[eB] : make_uint2(0u,0u);
    uint4 vA = *(const uint4*)(T + (size_t)qA.x*128 + c0);
    uint4 vB = *(const uint4*)(T + (size_t)qB.x*128 + c0);
    float cA = __uint_as_float(qA.y);
    float cB = __uint_as_float(qB.y);
    const unsigned* wa = (const unsigned*)&vA;
    const unsigned* wb = (const unsigned*)&vB;
    #pragma unroll
    for(int wq=0; wq<4; wq++){
      unsigned ua = wa[wq], ub = wb[wq];
      acc[2*wq]   += cA*us2f((us16)(ua & 0xffffu)) + cB*us2f((us16)(ub & 0xffffu));
      acc[2*wq+1] += cA*us2f((us16)(ua >> 16))     + cB*us2f((us16)(ub >> 16));
    }
  }
  // reduce across the 4 groups
  #pragma unroll
  for(int j=0;j<8;j++){
    acc[j] += __shfl_xor(acc[j], 16, 64);
    acc[j] += __shfl_xor(acc[j], 32, 64);
  }
  if (g != 0) return;
  // epilogue on lanes 0..15: cols c0..c0+7
  float disr = dis[r]; float invdeg = disr*disr;
  uint4 us4 = *(const uint4*)(T + (size_t)r*128 + c0);
  const unsigned* uw = (const unsigned*)&us4;
  uint4 rs4 = make_uint4(0u,0u,0u,0u);
  if (resid) rs4 = *(const uint4*)(resid + (size_t)r*128 + c0);
  const unsigned* rw = (const unsigned*)&rs4;
  unsigned outw[4];
  #pragma unroll
  for(int wq=0; wq<4; wq++){
    int cc0 = c0 + 2*wq, cc1 = c0 + 2*wq + 1;
    float s0 = us2f((us16)(uw[wq] & 0xffffu));
    float s1 = us2f((us16)(uw[wq] >> 16));
    float o0 = acc[2*wq]  *disr + s0*invdeg + bias[cc0];
    float o1 = acc[2*wq+1]*disr + s1*invdeg + bias[cc1];
    float sc0 = gamma[cc0] * rsqrtf(rv[cc0] + 1e-5f);
    float sc1 = gamma[cc1] * rsqrtf(rv[cc1] + 1e-5f);
    o0 = (o0 - rm[cc0])*sc0 + beta[cc0];
    o1 = (o1 - rm[cc1])*sc1 + beta[cc1];
    if (relu){ o0=fmaxf(o0,0.f); o1=fmaxf(o1,0.f); }
    if (resid){
      o0 += us2f((us16)(rw[wq] & 0xffffu));
      o1 += us2f((us16)(rw[wq] >> 16));
    }
    outw[wq] = (unsigned)f2us(o0) | ((unsigned)f2us(o1) << 16);
  }
  *(uint4*)(out + (size_t)r*128 + c0) = *(const uint4*)outw;
}

// ------------- seed constant (R9-exact) -------------
__global__ void k_const64(const us16* __restrict__ X0, const us16* __restrict__ X1,
                          const int* __restrict__ seed,
                          const float* __restrict__ pw1, const float* __restrict__ pb1,
                          float* __restrict__ c64){
  int j = threadIdx.x;  // 64 threads
  int s = seed[0];
  const us16* x0 = X0 + (size_t)s*128;
  const us16* x1 = X1 + (size_t)s*128;
  float acc = pb1[j];
  #pragma unroll 8
  for(int k=0;k<128;k++) acc += us2f(x0[k]) * pw1[(256+k)*64 + j];
  #pragma unroll 8
  for(int k=0;k<128;k++) acc += us2f(x1[k]) * pw1[(384+k)*64 + j];
  c64[j]=acc;
}

// ------------- final dot (R9-exact) -------------
__global__ __launch_bounds__(256) void k_outdot(const us16* __restrict__ Z2, const float* __restrict__ w3,
                                                const float* __restrict__ b3, float* __restrict__ out, int n){
  int r = blockIdx.x*256 + threadIdx.x;
  if(r>=n) return;
  const us16* z = Z2 + (size_t)r*64;
  float acc = b3[0];
  #pragma unroll 8
  for(int j=0;j<64;j++) acc += us2f(z[j])*w3[j];
  out[r]=acc;
}

extern "C" void kernel_launch(void* const* d_in, const int* in_sizes, int n_in,
                              void* d_out, int out_size, void* d_ws, size_t ws_size,
                              hipStream_t stream){
  const int N = N_NODES;
  const int E = in_sizes[2];
  const float* x   = (const float*)d_in[0];
  const int*   ei  = (const int*)d_in[1];
  const int*   et  = (const int*)d_in[2];
  const float* ew  = (const float*)d_in[3];
  const int*   seed= (const int*)d_in[4];
  const float* ft_w= (const float*)d_in[5];
  const float* ft_b= (const float*)d_in[6];
  const float* g0_w= (const float*)d_in[7];
  const float* g0_b= (const float*)d_in[8];
  const float* g0_g= (const float*)d_in[9];
  const float* g0_be=(const float*)d_in[10];
  const float* g0_rm=(const float*)d_in[11];
  const float* g0_rv=(const float*)d_in[12];
  const float* g1_w= (const float*)d_in[13];
  const float* g1_b= (const float*)d_in[14];
  const float* g1_g= (const float*)d_in[15];
  const float* g1_be=(const float*)d_in[16];
  const float* g1_rm=(const float*)d_in[17];
  const float* g1_rv=(const float*)d_in[18];
  const float* p_w1= (const float*)d_in[19];
  const float* p_b1= (const float*)d_in[20];
  const float* p_w2= (const float*)d_in[21];
  const float* p_b2= (const float*)d_in[22];
  const float* p_w3= (const float*)d_in[23];
  const float* p_b3= (const float*)d_in[24];
  float* out = (float*)d_out;

  // Footprint ~117.8 MB (< proven 119.2 MB). eofs aliases dead B0.
  char* wsp = (char*)d_ws;
  auto alloc = [&](size_t bytes)->char*{ char* p = wsp; wsp += (bytes + 255) & ~(size_t)255; return p; };
  us16* B0 = (us16*)alloc((size_t)N*128*2);
  us16* B1 = (us16*)alloc((size_t)N*128*2);
  us16* B2 = (us16*)alloc((size_t)N*128*2);
  us16* B3 = (us16*)alloc((size_t)N*128*2);
  uint2* csr = (uint2*)alloc((size_t)E*8);
  float* disA=(float*)alloc((size_t)2*N*4);
  int* cnt =(int*)alloc((size_t)2*N*4);
  int* rp  =(int*)alloc((size_t)2*N*4);
  int* bsum=(int*)alloc(4096);
  float* c64=(float*)alloc(256);
  us16* wt =(us16*)alloc((size_t)102400*2);
  int* eofs = (int*)B0;          // E*4 = 6.4MB <= B0's 25.6MB; B0 first written after fill
  us16* Z1 = B0;
  us16* Z2 = B1;

  const int* srcp = ei;
  const int* dstp = ei + E;

  // ---- graph preprocessing: count(+rank) -> scan -> fill(no atomic) -> deg -> fold dis[s] ----
  int M = 2*N;
  k_init<<<(M+255)/256,256,0,stream>>>(cnt,M);
  k_cnt<<<(E+255)/256,256,0,stream>>>(dstp,et,cnt,eofs,E);
  int SB = (M+2047)/2048;
  k_scan_reduce<<<SB,256,0,stream>>>(cnt,bsum,M);
  k_scan_top<<<1,64,0,stream>>>(bsum,SB);
  k_scan_apply<<<SB,256,0,stream>>>(cnt,bsum,rp,M);
  k_edge_fill<<<(E+255)/256,256,0,stream>>>(srcp,dstp,et,ew,rp,eofs,csr,E);
  k_deg_csr<<<(M+255)/256,256,0,stream>>>(csr,rp,cnt,disA,M);
  k_coef<<<(E+255)/256,256,0,stream>>>(csr,rp,disA,E);

  // ---- weight prep ----
  dim3 pg(64,7);
  k_prepw<<<pg,256,0,stream>>>(ft_w,g0_w,g1_w,p_w1,p_w2,wt);

  const us16* wt_ft = wt;
  const us16* wt_g00= wt+16384;
  const us16* wt_g01= wt+32768;
  const us16* wt_g10= wt+49152;
  const us16* wt_g11= wt+65536;
  const us16* wt_p1 = wt+81920;
  const us16* wt_p2 = wt+98304;
  const float* dis0 = disA;
  const float* dis1 = disA + N;

  int GB = (N+127)/128;
  int AB = (N+3)/4;
  // ---- feature transform: B0 = relu(x@ft_w + ft_b), f32 x staged directly ----
  k_mgemm<128,float><<<GB,256,0,stream>>>(x,x,128, wt_ft, ft_b, nullptr, B0,128, N,128,1);
  // ---- both blocks' layer-0 linear ----
  k_mgemm<128,us16><<<GB,256,0,stream>>>(B0,B0,128, wt_g00, nullptr,nullptr, B1,128, N,128,0);
  k_mgemm<128,us16><<<GB,256,0,stream>>>(B0,B0,128, wt_g10, nullptr,nullptr, B2,128, N,128,0);
  // ---- block 0 ----
  k_agg<<<AB,256,0,stream>>>(B1,csr,rp,cnt,0,dis0,
                             g0_b,g0_g,g0_be,g0_rm,g0_rv, nullptr, B0,1,N);      // h0 -> B0
  k_mgemm<128,us16><<<GB,256,0,stream>>>(B0,B0,128, wt_g01, nullptr,nullptr, B1,128, N,128,0);
  k_agg<<<AB,256,0,stream>>>(B1,csr,rp,cnt,0,dis0,
                             g0_b+128,g0_g+128,g0_be+128,g0_rm+128,g0_rv+128, B0, B3,0,N); // x0 -> B3
  // ---- block 1 ----
  k_agg<<<AB,256,0,stream>>>(B2,csr,rp,cnt,N,dis1,
                             g1_b,g1_g,g1_be,g1_rm,g1_rv, nullptr, B0,1,N);      // h1 -> B0
  k_mgemm<128,us16><<<GB,256,0,stream>>>(B0,B0,128, wt_g11, nullptr,nullptr, B1,128, N,128,0);
  k_agg<<<AB,256,0,stream>>>(B1,csr,rp,cnt,N,dis1,
                             g1_b+128,g1_g+128,g1_be+128,g1_rm+128,g1_rv+128, B0, B2,0,N); // x1 -> B2
  // ---- predictor ----
  k_const64<<<1,64,0,stream>>>(B3,B2,seed,p_w1,p_b1,c64);
  k_mgemm<64,us16><<<GB,256,0,stream>>>(B3,B2,128, wt_p1, nullptr, c64, Z1,64, N,256,1);
  k_mgemm<64,us16><<<GB,256,0,stream>>>(Z1,Z1,64,  wt_p2, p_b2, nullptr, Z2,64, N,64,1);
  k_outdot<<<(N+255)/256,256,0,stream>>>(Z2,p_w3,p_b3,out,N);
}

// Round 11
// 494.959 us; speedup vs baseline: 1.0813x; 1.0813x over previous
//
#include <hip/hip_runtime.h>
#include <hip/hip_bf16.h>
#include <stdint.h>

#define N_NODES 100000

typedef unsigned short us16;
typedef short bf16x8 __attribute__((ext_vector_type(8)));
typedef float f32x4 __attribute__((ext_vector_type(4)));

__device__ __forceinline__ float us2f(us16 u){
  union{ unsigned int i; float f; } x; x.i = ((unsigned int)u) << 16; return x.f;
}
__device__ __forceinline__ us16 f2us(float f){
  union{ float f; unsigned int i; } x; x.f = f;
  unsigned int i = x.i;
  unsigned int r = (i + 0x7FFFu + ((i >> 16) & 1u)) >> 16;
  return (us16)r;
}

// ---------------- init: zero cnt ----------------
__global__ __launch_bounds__(256) void k_init(int* __restrict__ cnt, int n2){
  int i = blockIdx.x*256 + threadIdx.x;
  if (i < n2) cnt[i]=0;
}

// ------- per-(type,dst) counts: ONE int atomic per edge; rank stored coalesced -------
__global__ __launch_bounds__(256) void k_cnt(const int* __restrict__ dst,
                                             const int* __restrict__ et,
                                             int* __restrict__ cnt,
                                             int* __restrict__ eofs, int E){
  int e = blockIdx.x*256 + threadIdx.x;
  if (e>=E) return;
  int d = dst[e]; int t = et[e];
  eofs[e] = atomicAdd(&cnt[t*N_NODES + d], 1);
}

// ---------------- exclusive scan over M elements (R1-exact) ----------------
__global__ __launch_bounds__(256) void k_scan_reduce(const int* __restrict__ in, int* __restrict__ bsum, int M){
  __shared__ int sd[256];
  int base = blockIdx.x*2048; int t = threadIdx.x;
  int sum = 0;
  #pragma unroll
  for(int i=0;i<8;i++){ int p = base + t*8 + i; if(p<M) sum += in[p]; }
  sd[t]=sum; __syncthreads();
  for(int s=128;s>0;s>>=1){ if(t<s) sd[t]+=sd[t+s]; __syncthreads(); }
  if(t==0) bsum[blockIdx.x]=sd[0];
}
__global__ void k_scan_top(int* __restrict__ bsum, int B){
  if (threadIdx.x==0){ int run=0; for(int i=0;i<B;i++){ int v=bsum[i]; bsum[i]=run; run+=v; } }
}
__global__ __launch_bounds__(256) void k_scan_apply(const int* __restrict__ in, const int* __restrict__ bsum,
                                                    int* __restrict__ out, int M){
  __shared__ int sd[256];
  int base = blockIdx.x*2048; int t = threadIdx.x;
  int loc[8]; int sum=0;
  #pragma unroll
  for(int i=0;i<8;i++){ int p = base + t*8 + i; int v = (p<M)?in[p]:0; loc[i]=sum; sum+=v; }
  sd[t]=sum; __syncthreads();
  for(int ofs=1;ofs<256;ofs<<=1){
    int v = (t>=ofs)? sd[t-ofs] : 0;
    __syncthreads();
    sd[t]+=v;
    __syncthreads();
  }
  int excl = ((t==0)?0:sd[t-1]) + bsum[blockIdx.x];
  #pragma unroll
  for(int i=0;i<8;i++){ int p = base + t*8 + i; if(p<M) out[p]=excl+loc[i]; }
}

// ---------------- CSR fill: NO atomic (pos = rp + precomputed rank); stores RAW w ----------------
__global__ __launch_bounds__(256) void k_edge_fill(const int* __restrict__ src, const int* __restrict__ dst,
  const int* __restrict__ et, const float* __restrict__ ew,
  const int* __restrict__ rp, const int* __restrict__ eofs,
  uint2* __restrict__ csr, int E){
  int e = blockIdx.x*256+threadIdx.x;
  if(e>=E) return;
  int s=src[e], d=dst[e], t=et[e]; float w=ew[e];
  int idx = t*N_NODES + d;
  int pos = rp[idx] + eofs[e];
  csr[pos] = make_uint2((unsigned)s, __float_as_uint(w));
}

// ---------------- degree from CSR (sequential, atomic-free) ----------------
__global__ __launch_bounds__(256) void k_deg_csr(const uint2* __restrict__ csr,
                                                 const int* __restrict__ rp, const int* __restrict__ cnt,
                                                 float* __restrict__ disA, int M){
  int i = blockIdx.x*256+threadIdx.x;
  if(i>=M) return;
  int e0 = rp[i], c = cnt[i];
  float s = 1.0f;
  for(int e=e0; e<e0+c; e++) s += __uint_as_float(csr[e].y);
  disA[i] = rsqrtf(s);
}

// ---------------- weight prep: f32 [K][NC] -> bf16 transposed [NC][K] ----------------
__global__ __launch_bounds__(256) void k_prepw(const float* __restrict__ ft_w,
                                               const float* __restrict__ g0_w, const float* __restrict__ g1_w,
                                               const float* __restrict__ p_w1, const float* __restrict__ p_w2,
                                               us16* __restrict__ wt){
  int m = blockIdx.y;
  const float* srcp; int K, NCc; us16* dstp;
  switch(m){
    case 0: srcp=ft_w;        K=128; NCc=128; dstp=wt;        break;
    case 1: srcp=g0_w;        K=128; NCc=128; dstp=wt+16384;  break;
    case 2: srcp=g0_w+16384;  K=128; NCc=128; dstp=wt+32768;  break;
    case 3: srcp=g1_w;        K=128; NCc=128; dstp=wt+49152;  break;
    case 4: srcp=g1_w+16384;  K=128; NCc=128; dstp=wt+65536;  break;
    case 5: srcp=p_w1;        K=256; NCc=64;  dstp=wt+81920;  break;
    default:srcp=p_w2;        K=64;  NCc=64;  dstp=wt+98304;  break;
  }
  int idx = blockIdx.x*256+threadIdx.x;
  if(idx >= K*NCc) return;
  int nn = idx / K, k = idx - nn*K;
  dstp[idx] = f2us(srcp[(size_t)k*NCc + nn]);
}

// ---------- MFMA GEMM (R6-verified core): C[n,NC](bf16) = (A@W) * rowscale (+bias/addv, relu) ----------
template<int NC, typename AT>
__global__ __launch_bounds__(256) void k_mgemm(const AT* __restrict__ A0, const AT* __restrict__ A1,
                 int lda, const us16* __restrict__ Wt,
                 const float* __restrict__ bias, const float* __restrict__ addv,
                 const float* __restrict__ rowscale,
                 us16* __restrict__ C, int ldc, int n, int KC, int relu){
  constexpr int NB = NC/16;
  __shared__ us16 Alds[128*64];
  __shared__ us16 Wlds[NC*64];
  const int tid = threadIdx.x;
  const int lane = tid & 63, wid = tid >> 6;
  const int rowBase = blockIdx.x*128;
  f32x4 zero = {0.f,0.f,0.f,0.f};
  f32x4 acc[2][NB];
  #pragma unroll
  for(int m=0;m<2;m++)
    #pragma unroll
    for(int nb=0;nb<NB;nb++) acc[m][nb] = zero;

  for(int kk=0; kk<KC; kk+=64){
    const AT* Ab = (kk<128)? A0 : A1;
    const int kc = (kk<128)? kk : (kk-128);
    #pragma unroll
    for(int p=0;p<4;p++){
      int idx = p*256 + tid;
      int r = idx>>3, u = idx&7;
      int row = rowBase + r;
      uint4 v = make_uint4(0u,0u,0u,0u);
      if(row<n){
        if constexpr (sizeof(AT)==2){
          v = *(const uint4*)(Ab + (size_t)row*lda + kc + u*8);
        } else {
          float4 f0 = *(const float4*)(Ab + (size_t)row*lda + kc + u*8);
          float4 f1 = *(const float4*)(Ab + (size_t)row*lda + kc + u*8 + 4);
          us16 tmp[8] = {f2us(f0.x),f2us(f0.y),f2us(f0.z),f2us(f0.w),
                         f2us(f1.x),f2us(f1.y),f2us(f1.z),f2us(f1.w)};
          v = *(const uint4*)tmp;
        }
      }
      *(uint4*)&Alds[(r*8 + (u ^ (r&7)))*8] = v;
    }
    #pragma unroll
    for(int p=0;p<NB/2;p++){
      int idx = p*256 + tid;
      int cI = idx>>3, u = idx&7;
      uint4 v = *(const uint4*)(Wt + (size_t)cI*KC + kk + u*8);
      *(uint4*)&Wlds[(cI*8 + (u ^ (cI&7)))*8] = v;
    }
    __syncthreads();
    #pragma unroll
    for(int ks=0;ks<2;ks++){
      bf16x8 af[2];
      #pragma unroll
      for(int m=0;m<2;m++){
        int r = wid*32 + m*16 + (lane&15);
        int u = (ks*4 + (lane>>4)) ^ (r&7);
        af[m] = *(const bf16x8*)&Alds[(r*8+u)*8];
      }
      #pragma unroll
      for(int nb=0;nb<NB;nb++){
        int c2 = nb*16 + (lane&15);
        int u = (ks*4 + (lane>>4)) ^ (c2&7);
        bf16x8 bfv = *(const bf16x8*)&Wlds[(c2*8+u)*8];
        #pragma unroll
        for(int m=0;m<2;m++)
          acc[m][nb] = __builtin_amdgcn_mfma_f32_16x16x32_bf16(af[m], bfv, acc[m][nb], 0,0,0);
      }
    }
    __syncthreads();
  }
  // per-row scale hoisted: row depends on (m,j) only
  float rs[2][4];
  #pragma unroll
  for(int m=0;m<2;m++)
    #pragma unroll
    for(int j=0;j<4;j++){
      int row = rowBase + wid*32 + m*16 + (lane>>4)*4 + j;
      rs[m][j] = (rowscale && row<n) ? rowscale[row] : 1.0f;
    }
  #pragma unroll
  for(int nb=0;nb<NB;nb++){
    int col = nb*16 + (lane&15);
    float badd = (bias? bias[col]:0.f) + (addv? addv[col]:0.f);
    #pragma unroll
    for(int m=0;m<2;m++){
      #pragma unroll
      for(int j=0;j<4;j++){
        int row = rowBase + wid*32 + m*16 + (lane>>4)*4 + j;
        if(row<n){
          float v = acc[m][nb][j]*rs[m][j] + badd;
          if(relu) v = fmaxf(v,0.f);
          C[(size_t)row*ldc + col] = f2us(v);
        }
      }
    }
  }
}

// --- aggregation (R9-proven chunk-4; T is pre-scaled by dis): out = dis_r*(Σ w*T'[s] + T'[r]) + bias, BN ---
__global__ __launch_bounds__(256) void k_agg(const us16* __restrict__ T,
  const uint2* __restrict__ csr,
  const int* __restrict__ rp, const int* __restrict__ cnt, int rowOfs,
  const float* __restrict__ dis,
  const float* __restrict__ bias, const float* __restrict__ gamma, const float* __restrict__ beta,
  const float* __restrict__ rm, const float* __restrict__ rv,
  const us16* __restrict__ resid,
  us16* __restrict__ out, int relu, int n){
  int wid = threadIdx.x >> 6, lane = threadIdx.x & 63;
  int r = blockIdx.x*4 + wid;
  if (r >= n) return;
  int c0 = lane*2;
  int idx = rowOfs + r;
  int e0 = rp[idx];
  int ec = cnt[idx];
  const uint2* cp = csr + e0;
  float acc0=0.f, acc1=0.f;
  int nchunk = ec >> 2;
  int rem = ec & 3;
  for(int ch=0; ch<nchunk; ch++){
    uint2 q0 = cp[0], q1 = cp[1], q2 = cp[2], q3 = cp[3];
    cp += 4;
    unsigned ua = *(const unsigned int*)(T + (size_t)q0.x*128 + c0);
    unsigned ub = *(const unsigned int*)(T + (size_t)q1.x*128 + c0);
    unsigned uc = *(const unsigned int*)(T + (size_t)q2.x*128 + c0);
    unsigned ud = *(const unsigned int*)(T + (size_t)q3.x*128 + c0);
    float ca = __uint_as_float(q0.y), cb = __uint_as_float(q1.y);
    float cc = __uint_as_float(q2.y), cd = __uint_as_float(q3.y);
    acc0 += ca*us2f((us16)(ua & 0xffffu));
    acc1 += ca*us2f((us16)(ua >> 16));
    acc0 += cb*us2f((us16)(ub & 0xffffu));
    acc1 += cb*us2f((us16)(ub >> 16));
    acc0 += cc*us2f((us16)(uc & 0xffffu));
    acc1 += cc*us2f((us16)(uc >> 16));
    acc0 += cd*us2f((us16)(ud & 0xffffu));
    acc1 += cd*us2f((us16)(ud >> 16));
  }
  for(int i=0;i<rem;i++){
    uint2 q = cp[i];
    float c = __uint_as_float(q.y);
    unsigned u = *(const unsigned int*)(T + (size_t)q.x*128 + c0);
    acc0 += c*us2f((us16)(u & 0xffffu));
    acc1 += c*us2f((us16)(u >> 16));
  }
  // self-loop: T'[r] with coefficient 1 (dis_r * T'[r] == T[r]/deg)
  unsigned int uself = *(const unsigned int*)(T + (size_t)r*128 + c0);
  acc0 += us2f((us16)(uself & 0xffffu));
  acc1 += us2f((us16)(uself >> 16));
  float disr = dis[r];
  float o0 = acc0*disr + bias[c0];
  float o1 = acc1*disr + bias[c0+1];
  float sc0 = gamma[c0]  * rsqrtf(rv[c0]  + 1e-5f);
  float sc1 = gamma[c0+1]* rsqrtf(rv[c0+1]+ 1e-5f);
  o0 = (o0 - rm[c0])*sc0 + beta[c0];
  o1 = (o1 - rm[c0+1])*sc1 + beta[c0+1];
  if (relu){ o0=fmaxf(o0,0.f); o1=fmaxf(o1,0.f); }
  if (resid){
    unsigned int ur = *(const unsigned int*)(resid + (size_t)r*128 + c0);
    o0 += us2f((us16)(ur & 0xffffu));
    o1 += us2f((us16)(ur >> 16));
  }
  unsigned int up = (unsigned int)f2us(o0) | ((unsigned int)f2us(o1) << 16);
  *(unsigned int*)(out + (size_t)r*128 + c0) = up;
}

// ------------- seed constant (R9-exact) -------------
__global__ void k_const64(const us16* __restrict__ X0, const us16* __restrict__ X1,
                          const int* __restrict__ seed,
                          const float* __restrict__ pw1, const float* __restrict__ pb1,
                          float* __restrict__ c64){
  int j = threadIdx.x;  // 64 threads
  int s = seed[0];
  const us16* x0 = X0 + (size_t)s*128;
  const us16* x1 = X1 + (size_t)s*128;
  float acc = pb1[j];
  #pragma unroll 8
  for(int k=0;k<128;k++) acc += us2f(x0[k]) * pw1[(256+k)*64 + j];
  #pragma unroll 8
  for(int k=0;k<128;k++) acc += us2f(x1[k]) * pw1[(384+k)*64 + j];
  c64[j]=acc;
}

// ------------- final dot (R9-exact) -------------
__global__ __launch_bounds__(256) void k_outdot(const us16* __restrict__ Z2, const float* __restrict__ w3,
                                                const float* __restrict__ b3, float* __restrict__ out, int n){
  int r = blockIdx.x*256 + threadIdx.x;
  if(r>=n) return;
  const us16* z = Z2 + (size_t)r*64;
  float acc = b3[0];
  #pragma unroll 8
  for(int j=0;j<64;j++) acc += us2f(z[j])*w3[j];
  out[r]=acc;
}

extern "C" void kernel_launch(void* const* d_in, const int* in_sizes, int n_in,
                              void* d_out, int out_size, void* d_ws, size_t ws_size,
                              hipStream_t stream){
  const int N = N_NODES;
  const int E = in_sizes[2];
  const float* x   = (const float*)d_in[0];
  const int*   ei  = (const int*)d_in[1];
  const int*   et  = (const int*)d_in[2];
  const float* ew  = (const float*)d_in[3];
  const int*   seed= (const int*)d_in[4];
  const float* ft_w= (const float*)d_in[5];
  const float* ft_b= (const float*)d_in[6];
  const float* g0_w= (const float*)d_in[7];
  const float* g0_b= (const float*)d_in[8];
  const float* g0_g= (const float*)d_in[9];
  const float* g0_be=(const float*)d_in[10];
  const float* g0_rm=(const float*)d_in[11];
  const float* g0_rv=(const float*)d_in[12];
  const float* g1_w= (const float*)d_in[13];
  const float* g1_b= (const float*)d_in[14];
  const float* g1_g= (const float*)d_in[15];
  const float* g1_be=(const float*)d_in[16];
  const float* g1_rm=(const float*)d_in[17];
  const float* g1_rv=(const float*)d_in[18];
  const float* p_w1= (const float*)d_in[19];
  const float* p_b1= (const float*)d_in[20];
  const float* p_w2= (const float*)d_in[21];
  const float* p_b2= (const float*)d_in[22];
  const float* p_w3= (const float*)d_in[23];
  const float* p_b3= (const float*)d_in[24];
  float* out = (float*)d_out;

  // Footprint ~117.8 MB (< proven 119.2 MB). eofs aliases dead B0.
  char* wsp = (char*)d_ws;
  auto alloc = [&](size_t bytes)->char*{ char* p = wsp; wsp += (bytes + 255) & ~(size_t)255; return p; };
  us16* B0 = (us16*)alloc((size_t)N*128*2);
  us16* B1 = (us16*)alloc((size_t)N*128*2);
  us16* B2 = (us16*)alloc((size_t)N*128*2);
  us16* B3 = (us16*)alloc((size_t)N*128*2);
  uint2* csr = (uint2*)alloc((size_t)E*8);
  float* disA=(float*)alloc((size_t)2*N*4);
  int* cnt =(int*)alloc((size_t)2*N*4);
  int* rp  =(int*)alloc((size_t)2*N*4);
  int* bsum=(int*)alloc(4096);
  float* c64=(float*)alloc(256);
  us16* wt =(us16*)alloc((size_t)102400*2);
  int* eofs = (int*)B0;          // E*4 = 6.4MB <= B0's 25.6MB; B0 first written after fill
  us16* Z1 = B0;
  us16* Z2 = B1;

  const int* srcp = ei;
  const int* dstp = ei + E;

  // ---- graph preprocessing: count(+rank) -> scan -> fill(raw w, no atomic) -> deg ----
  int M = 2*N;
  k_init<<<(M+255)/256,256,0,stream>>>(cnt,M);
  k_cnt<<<(E+255)/256,256,0,stream>>>(dstp,et,cnt,eofs,E);
  int SB = (M+2047)/2048;
  k_scan_reduce<<<SB,256,0,stream>>>(cnt,bsum,M);
  k_scan_top<<<1,64,0,stream>>>(bsum,SB);
  k_scan_apply<<<SB,256,0,stream>>>(cnt,bsum,rp,M);
  k_edge_fill<<<(E+255)/256,256,0,stream>>>(srcp,dstp,et,ew,rp,eofs,csr,E);
  k_deg_csr<<<(M+255)/256,256,0,stream>>>(csr,rp,cnt,disA,M);

  // ---- weight prep ----
  dim3 pg(64,7);
  k_prepw<<<pg,256,0,stream>>>(ft_w,g0_w,g1_w,p_w1,p_w2,wt);

  const us16* wt_ft = wt;
  const us16* wt_g00= wt+16384;
  const us16* wt_g01= wt+32768;
  const us16* wt_g10= wt+49152;
  const us16* wt_g11= wt+65536;
  const us16* wt_p1 = wt+81920;
  const us16* wt_p2 = wt+98304;
  const float* dis0 = disA;
  const float* dis1 = disA + N;

  int GB = (N+127)/128;
  int AB = (N+3)/4;
  // ---- feature transform: B0 = relu(x@ft_w + ft_b), f32 x staged directly ----
  k_mgemm<128,float><<<GB,256,0,stream>>>(x,x,128, wt_ft, ft_b, nullptr, nullptr, B0,128, N,128,1);
  // ---- both blocks' layer-0 linear, dis-scaled: T' = (h@W)*dis ----
  k_mgemm<128,us16><<<GB,256,0,stream>>>(B0,B0,128, wt_g00, nullptr,nullptr, dis0, B1,128, N,128,0);
  k_mgemm<128,us16><<<GB,256,0,stream>>>(B0,B0,128, wt_g10, nullptr,nullptr, dis1, B2,128, N,128,0);
  // ---- block 0 ----
  k_agg<<<AB,256,0,stream>>>(B1,csr,rp,cnt,0,dis0,
                             g0_b,g0_g,g0_be,g0_rm,g0_rv, nullptr, B0,1,N);      // h0 -> B0
  k_mgemm<128,us16><<<GB,256,0,stream>>>(B0,B0,128, wt_g01, nullptr,nullptr, dis0, B1,128, N,128,0);
  k_agg<<<AB,256,0,stream>>>(B1,csr,rp,cnt,0,dis0,
                             g0_b+128,g0_g+128,g0_be+128,g0_rm+128,g0_rv+128, B0, B3,0,N); // x0 -> B3
  // ---- block 1 ----
  k_agg<<<AB,256,0,stream>>>(B2,csr,rp,cnt,N,dis1,
                             g1_b,g1_g,g1_be,g1_rm,g1_rv, nullptr, B0,1,N);      // h1 -> B0
  k_mgemm<128,us16><<<GB,256,0,stream>>>(B0,B0,128, wt_g11, nullptr,nullptr, dis1, B1,128, N,128,0);
  k_agg<<<AB,256,0,stream>>>(B1,csr,rp,cnt,N,dis1,
                             g1_b+128,g1_g+128,g1_be+128,g1_rm+128,g1_rv+128, B0, B2,0,N); // x1 -> B2
  // ---- predictor ----
  k_const64<<<1,64,0,stream>>>(B3,B2,seed,p_w1,p_b1,c64);
  k_mgemm<64,us16><<<GB,256,0,stream>>>(B3,B2,128, wt_p1, nullptr, c64, nullptr, Z1,64, N,256,1);
  k_mgemm<64,us16><<<GB,256,0,stream>>>(Z1,Z1,64,  wt_p2, p_b2, nullptr, nullptr, Z2,64, N,64,1);
  k_outdot<<<(N+255)/256,256,0,stream>>>(Z2,p_w3,p_b3,out,N);
}

// Round 12
// 444.977 us; speedup vs baseline: 1.2027x; 1.1123x over previous
//
#include <hip/hip_runtime.h>
#include <hip/hip_bf16.h>
#include <stdint.h>

#define N_NODES 100000

typedef unsigned short us16;
typedef short bf16x8 __attribute__((ext_vector_type(8)));
typedef float f32x4 __attribute__((ext_vector_type(4)));

__device__ __forceinline__ float us2f(us16 u){
  union{ unsigned int i; float f; } x; x.i = ((unsigned int)u) << 16; return x.f;
}
__device__ __forceinline__ us16 f2us(float f){
  union{ float f; unsigned int i; } x; x.f = f;
  unsigned int i = x.i;
  unsigned int r = (i + 0x7FFFu + ((i >> 16) & 1u)) >> 16;
  return (us16)r;
}

// ---------------- init: zero cnt ----------------
__global__ __launch_bounds__(256) void k_init(int* __restrict__ cnt, int n2){
  int i = blockIdx.x*256 + threadIdx.x;
  if (i < n2) cnt[i]=0;
}

// ------- per-(type,dst) counts: ONE int atomic per edge; rank stored coalesced -------
__global__ __launch_bounds__(256) void k_cnt(const int* __restrict__ dst,
                                             const int* __restrict__ et,
                                             int* __restrict__ cnt,
                                             int* __restrict__ eofs, int E){
  int e = blockIdx.x*256 + threadIdx.x;
  if (e>=E) return;
  int d = dst[e]; int t = et[e];
  eofs[e] = atomicAdd(&cnt[t*N_NODES + d], 1);
}

// ---------------- exclusive scan over M elements (R1-exact) ----------------
__global__ __launch_bounds__(256) void k_scan_reduce(const int* __restrict__ in, int* __restrict__ bsum, int M){
  __shared__ int sd[256];
  int base = blockIdx.x*2048; int t = threadIdx.x;
  int sum = 0;
  #pragma unroll
  for(int i=0;i<8;i++){ int p = base + t*8 + i; if(p<M) sum += in[p]; }
  sd[t]=sum; __syncthreads();
  for(int s=128;s>0;s>>=1){ if(t<s) sd[t]+=sd[t+s]; __syncthreads(); }
  if(t==0) bsum[blockIdx.x]=sd[0];
}
__global__ void k_scan_top(int* __restrict__ bsum, int B){
  if (threadIdx.x==0){ int run=0; for(int i=0;i<B;i++){ int v=bsum[i]; bsum[i]=run; run+=v; } }
}
__global__ __launch_bounds__(256) void k_scan_apply(const int* __restrict__ in, const int* __restrict__ bsum,
                                                    int* __restrict__ out, int M){
  __shared__ int sd[256];
  int base = blockIdx.x*2048; int t = threadIdx.x;
  int loc[8]; int sum=0;
  #pragma unroll
  for(int i=0;i<8;i++){ int p = base + t*8 + i; int v = (p<M)?in[p]:0; loc[i]=sum; sum+=v; }
  sd[t]=sum; __syncthreads();
  for(int ofs=1;ofs<256;ofs<<=1){
    int v = (t>=ofs)? sd[t-ofs] : 0;
    __syncthreads();
    sd[t]+=v;
    __syncthreads();
  }
  int excl = ((t==0)?0:sd[t-1]) + bsum[blockIdx.x];
  #pragma unroll
  for(int i=0;i<8;i++){ int p = base + t*8 + i; if(p<M) out[p]=excl+loc[i]; }
}

// ---------------- CSR fill: NO atomic (pos = rp + precomputed rank); stores RAW w ----------------
__global__ __launch_bounds__(256) void k_edge_fill(const int* __restrict__ src, const int* __restrict__ dst,
  const int* __restrict__ et, const float* __restrict__ ew,
  const int* __restrict__ rp, const int* __restrict__ eofs,
  uint2* __restrict__ csr, int E){
  int e = blockIdx.x*256+threadIdx.x;
  if(e>=E) return;
  int s=src[e], d=dst[e], t=et[e]; float w=ew[e];
  int idx = t*N_NODES + d;
  int pos = rp[idx] + eofs[e];
  csr[pos] = make_uint2((unsigned)s, __float_as_uint(w));
}

// ---------------- degree from CSR (sequential, atomic-free) ----------------
__global__ __launch_bounds__(256) void k_deg_csr(const uint2* __restrict__ csr,
                                                 const int* __restrict__ rp, const int* __restrict__ cnt,
                                                 float* __restrict__ disA, int M){
  int i = blockIdx.x*256+threadIdx.x;
  if(i>=M) return;
  int e0 = rp[i], c = cnt[i];
  float s = 1.0f;
  for(int e=e0; e<e0+c; e++) s += __uint_as_float(csr[e].y);
  disA[i] = rsqrtf(s);
}

// ---------------- weight prep: f32 [K][NC] -> bf16 transposed [NC][K] ----------------
__global__ __launch_bounds__(256) void k_prepw(const float* __restrict__ ft_w,
                                               const float* __restrict__ g0_w, const float* __restrict__ g1_w,
                                               const float* __restrict__ p_w1, const float* __restrict__ p_w2,
                                               us16* __restrict__ wt){
  int m = blockIdx.y;
  const float* srcp; int K, NCc; us16* dstp;
  switch(m){
    case 0: srcp=ft_w;        K=128; NCc=128; dstp=wt;        break;
    case 1: srcp=g0_w;        K=128; NCc=128; dstp=wt+16384;  break;
    case 2: srcp=g0_w+16384;  K=128; NCc=128; dstp=wt+32768;  break;
    case 3: srcp=g1_w;        K=128; NCc=128; dstp=wt+49152;  break;
    case 4: srcp=g1_w+16384;  K=128; NCc=128; dstp=wt+65536;  break;
    case 5: srcp=p_w1;        K=256; NCc=64;  dstp=wt+81920;  break;
    default:srcp=p_w2;        K=64;  NCc=64;  dstp=wt+98304;  break;
  }
  int idx = blockIdx.x*256+threadIdx.x;
  if(idx >= K*NCc) return;
  int nn = idx / K, k = idx - nn*K;
  dstp[idx] = f2us(srcp[(size_t)k*NCc + nn]);
}

// ---------- MFMA GEMM (R6-verified core): C[n,NC](bf16) = (A@W) * rowscale (+bias/addv, relu) ----------
template<int NC, typename AT>
__global__ __launch_bounds__(256) void k_mgemm(const AT* __restrict__ A0, const AT* __restrict__ A1,
                 int lda, const us16* __restrict__ Wt,
                 const float* __restrict__ bias, const float* __restrict__ addv,
                 const float* __restrict__ rowscale,
                 us16* __restrict__ C, int ldc, int n, int KC, int relu){
  constexpr int NB = NC/16;
  __shared__ us16 Alds[128*64];
  __shared__ us16 Wlds[NC*64];
  const int tid = threadIdx.x;
  const int lane = tid & 63, wid = tid >> 6;
  const int rowBase = blockIdx.x*128;
  f32x4 zero = {0.f,0.f,0.f,0.f};
  f32x4 acc[2][NB];
  #pragma unroll
  for(int m=0;m<2;m++)
    #pragma unroll
    for(int nb=0;nb<NB;nb++) acc[m][nb] = zero;

  for(int kk=0; kk<KC; kk+=64){
    const AT* Ab = (kk<128)? A0 : A1;
    const int kc = (kk<128)? kk : (kk-128);
    #pragma unroll
    for(int p=0;p<4;p++){
      int idx = p*256 + tid;
      int r = idx>>3, u = idx&7;
      int row = rowBase + r;
      uint4 v = make_uint4(0u,0u,0u,0u);
      if(row<n){
        if constexpr (sizeof(AT)==2){
          v = *(const uint4*)(Ab + (size_t)row*lda + kc + u*8);
        } else {
          float4 f0 = *(const float4*)(Ab + (size_t)row*lda + kc + u*8);
          float4 f1 = *(const float4*)(Ab + (size_t)row*lda + kc + u*8 + 4);
          us16 tmp[8] = {f2us(f0.x),f2us(f0.y),f2us(f0.z),f2us(f0.w),
                         f2us(f1.x),f2us(f1.y),f2us(f1.z),f2us(f1.w)};
          v = *(const uint4*)tmp;
        }
      }
      *(uint4*)&Alds[(r*8 + (u ^ (r&7)))*8] = v;
    }
    #pragma unroll
    for(int p=0;p<NB/2;p++){
      int idx = p*256 + tid;
      int cI = idx>>3, u = idx&7;
      uint4 v = *(const uint4*)(Wt + (size_t)cI*KC + kk + u*8);
      *(uint4*)&Wlds[(cI*8 + (u ^ (cI&7)))*8] = v;
    }
    __syncthreads();
    #pragma unroll
    for(int ks=0;ks<2;ks++){
      bf16x8 af[2];
      #pragma unroll
      for(int m=0;m<2;m++){
        int r = wid*32 + m*16 + (lane&15);
        int u = (ks*4 + (lane>>4)) ^ (r&7);
        af[m] = *(const bf16x8*)&Alds[(r*8+u)*8];
      }
      #pragma unroll
      for(int nb=0;nb<NB;nb++){
        int c2 = nb*16 + (lane&15);
        int u = (ks*4 + (lane>>4)) ^ (c2&7);
        bf16x8 bfv = *(const bf16x8*)&Wlds[(c2*8+u)*8];
        #pragma unroll
        for(int m=0;m<2;m++)
          acc[m][nb] = __builtin_amdgcn_mfma_f32_16x16x32_bf16(af[m], bfv, acc[m][nb], 0,0,0);
      }
    }
    __syncthreads();
  }
  float rs[2][4];
  #pragma unroll
  for(int m=0;m<2;m++)
    #pragma unroll
    for(int j=0;j<4;j++){
      int row = rowBase + wid*32 + m*16 + (lane>>4)*4 + j;
      rs[m][j] = (rowscale && row<n) ? rowscale[row] : 1.0f;
    }
  #pragma unroll
  for(int nb=0;nb<NB;nb++){
    int col = nb*16 + (lane&15);
    float badd = (bias? bias[col]:0.f) + (addv? addv[col]:0.f);
    #pragma unroll
    for(int m=0;m<2;m++){
      #pragma unroll
      for(int j=0;j<4;j++){
        int row = rowBase + wid*32 + m*16 + (lane>>4)*4 + j;
        if(row<n){
          float v = acc[m][nb][j]*rs[m][j] + badd;
          if(relu) v = fmaxf(v,0.f);
          C[(size_t)row*ldc + col] = f2us(v);
        }
      }
    }
  }
}

// --- aggregation: 2 rows/wave (half-wave per row), chunk-4, 8B gathers ---
// T is pre-scaled by dis: out = dis_r*(Σ w*T'[s] + T'[r]) + bias, BN, relu/resid.
__global__ __launch_bounds__(256) void k_agg(const us16* __restrict__ T,
  const uint2* __restrict__ csr,
  const int* __restrict__ rp, const int* __restrict__ cnt, int rowOfs,
  const float* __restrict__ dis,
  const float* __restrict__ bias, const float* __restrict__ gamma, const float* __restrict__ beta,
  const float* __restrict__ rm, const float* __restrict__ rv,
  const us16* __restrict__ resid,
  us16* __restrict__ out, int relu, int n){
  const int wid = threadIdx.x >> 6, lane = threadIdx.x & 63;
  const int hw = lane >> 5;        // half-wave index: which row
  const int sl = lane & 31;        // sublane within half
  int r = blockIdx.x*8 + wid*2 + hw;
  if (r >= n) return;
  const int c0 = sl*4;             // 4 bf16 cols = 8B
  int idx = rowOfs + r;
  int e0 = rp[idx];
  int ec = cnt[idx];
  const uint2* cp = csr + e0;
  float a0=0.f, a1=0.f, a2=0.f, a3=0.f;
  int nchunk = ec >> 2;
  int rem = ec & 3;
  for(int ch=0; ch<nchunk; ch++){
    uint2 q0 = cp[0], q1 = cp[1], q2 = cp[2], q3 = cp[3];
    cp += 4;
    uint2 va = *(const uint2*)(T + (size_t)q0.x*128 + c0);
    uint2 vb = *(const uint2*)(T + (size_t)q1.x*128 + c0);
    uint2 vc = *(const uint2*)(T + (size_t)q2.x*128 + c0);
    uint2 vd = *(const uint2*)(T + (size_t)q3.x*128 + c0);
    float ca = __uint_as_float(q0.y), cb = __uint_as_float(q1.y);
    float cc = __uint_as_float(q2.y), cd = __uint_as_float(q3.y);
    a0 += ca*us2f((us16)(va.x & 0xffffu));
    a1 += ca*us2f((us16)(va.x >> 16));
    a2 += ca*us2f((us16)(va.y & 0xffffu));
    a3 += ca*us2f((us16)(va.y >> 16));
    a0 += cb*us2f((us16)(vb.x & 0xffffu));
    a1 += cb*us2f((us16)(vb.x >> 16));
    a2 += cb*us2f((us16)(vb.y & 0xffffu));
    a3 += cb*us2f((us16)(vb.y >> 16));
    a0 += cc*us2f((us16)(vc.x & 0xffffu));
    a1 += cc*us2f((us16)(vc.x >> 16));
    a2 += cc*us2f((us16)(vc.y & 0xffffu));
    a3 += cc*us2f((us16)(vc.y >> 16));
    a0 += cd*us2f((us16)(vd.x & 0xffffu));
    a1 += cd*us2f((us16)(vd.x >> 16));
    a2 += cd*us2f((us16)(vd.y & 0xffffu));
    a3 += cd*us2f((us16)(vd.y >> 16));
  }
  for(int i=0;i<rem;i++){
    uint2 q = cp[i];
    float c = __uint_as_float(q.y);
    uint2 v = *(const uint2*)(T + (size_t)q.x*128 + c0);
    a0 += c*us2f((us16)(v.x & 0xffffu));
    a1 += c*us2f((us16)(v.x >> 16));
    a2 += c*us2f((us16)(v.y & 0xffffu));
    a3 += c*us2f((us16)(v.y >> 16));
  }
  // self-loop: T'[r] with coefficient 1 (dis_r * T'[r] == T[r]/deg)
  uint2 vs = *(const uint2*)(T + (size_t)r*128 + c0);
  a0 += us2f((us16)(vs.x & 0xffffu));
  a1 += us2f((us16)(vs.x >> 16));
  a2 += us2f((us16)(vs.y & 0xffffu));
  a3 += us2f((us16)(vs.y >> 16));
  float disr = dis[r];
  float4 bi = *(const float4*)(bias + c0);
  float4 ga = *(const float4*)(gamma + c0);
  float4 be = *(const float4*)(beta + c0);
  float4 rmv= *(const float4*)(rm + c0);
  float4 rvv= *(const float4*)(rv + c0);
  float o0 = a0*disr + bi.x;
  float o1 = a1*disr + bi.y;
  float o2 = a2*disr + bi.z;
  float o3 = a3*disr + bi.w;
  o0 = (o0 - rmv.x)*(ga.x*rsqrtf(rvv.x + 1e-5f)) + be.x;
  o1 = (o1 - rmv.y)*(ga.y*rsqrtf(rvv.y + 1e-5f)) + be.y;
  o2 = (o2 - rmv.z)*(ga.z*rsqrtf(rvv.z + 1e-5f)) + be.z;
  o3 = (o3 - rmv.w)*(ga.w*rsqrtf(rvv.w + 1e-5f)) + be.w;
  if (relu){
    o0=fmaxf(o0,0.f); o1=fmaxf(o1,0.f); o2=fmaxf(o2,0.f); o3=fmaxf(o3,0.f);
  }
  if (resid){
    uint2 vr = *(const uint2*)(resid + (size_t)r*128 + c0);
    o0 += us2f((us16)(vr.x & 0xffffu));
    o1 += us2f((us16)(vr.x >> 16));
    o2 += us2f((us16)(vr.y & 0xffffu));
    o3 += us2f((us16)(vr.y >> 16));
  }
  uint2 up;
  up.x = (unsigned)f2us(o0) | ((unsigned)f2us(o1) << 16);
  up.y = (unsigned)f2us(o2) | ((unsigned)f2us(o3) << 16);
  *(uint2*)(out + (size_t)r*128 + c0) = up;
}

// ------------- seed constant (R11-exact) -------------
__global__ void k_const64(const us16* __restrict__ X0, const us16* __restrict__ X1,
                          const int* __restrict__ seed,
                          const float* __restrict__ pw1, const float* __restrict__ pb1,
                          float* __restrict__ c64){
  int j = threadIdx.x;  // 64 threads
  int s = seed[0];
  const us16* x0 = X0 + (size_t)s*128;
  const us16* x1 = X1 + (size_t)s*128;
  float acc = pb1[j];
  #pragma unroll 8
  for(int k=0;k<128;k++) acc += us2f(x0[k]) * pw1[(256+k)*64 + j];
  #pragma unroll 8
  for(int k=0;k<128;k++) acc += us2f(x1[k]) * pw1[(384+k)*64 + j];
  c64[j]=acc;
}

// ------------- final dot (R11-exact) -------------
__global__ __launch_bounds__(256) void k_outdot(const us16* __restrict__ Z2, const float* __restrict__ w3,
                                                const float* __restrict__ b3, float* __restrict__ out, int n){
  int r = blockIdx.x*256 + threadIdx.x;
  if(r>=n) return;
  const us16* z = Z2 + (size_t)r*64;
  float acc = b3[0];
  #pragma unroll 8
  for(int j=0;j<64;j++) acc += us2f(z[j])*w3[j];
  out[r]=acc;
}

extern "C" void kernel_launch(void* const* d_in, const int* in_sizes, int n_in,
                              void* d_out, int out_size, void* d_ws, size_t ws_size,
                              hipStream_t stream){
  const int N = N_NODES;
  const int E = in_sizes[2];
  const float* x   = (const float*)d_in[0];
  const int*   ei  = (const int*)d_in[1];
  const int*   et  = (const int*)d_in[2];
  const float* ew  = (const float*)d_in[3];
  const int*   seed= (const int*)d_in[4];
  const float* ft_w= (const float*)d_in[5];
  const float* ft_b= (const float*)d_in[6];
  const float* g0_w= (const float*)d_in[7];
  const float* g0_b= (const float*)d_in[8];
  const float* g0_g= (const float*)d_in[9];
  const float* g0_be=(const float*)d_in[10];
  const float* g0_rm=(const float*)d_in[11];
  const float* g0_rv=(const float*)d_in[12];
  const float* g1_w= (const float*)d_in[13];
  const float* g1_b= (const float*)d_in[14];
  const float* g1_g= (const float*)d_in[15];
  const float* g1_be=(const float*)d_in[16];
  const float* g1_rm=(const float*)d_in[17];
  const float* g1_rv=(const float*)d_in[18];
  const float* p_w1= (const float*)d_in[19];
  const float* p_b1= (const float*)d_in[20];
  const float* p_w2= (const float*)d_in[21];
  const float* p_b2= (const float*)d_in[22];
  const float* p_w3= (const float*)d_in[23];
  const float* p_b3= (const float*)d_in[24];
  float* out = (float*)d_out;

  // Footprint ~117.8 MB (< proven 119.2 MB). eofs aliases dead B0.
  char* wsp = (char*)d_ws;
  auto alloc = [&](size_t bytes)->char*{ char* p = wsp; wsp += (bytes + 255) & ~(size_t)255; return p; };
  us16* B0 = (us16*)alloc((size_t)N*128*2);
  us16* B1 = (us16*)alloc((size_t)N*128*2);
  us16* B2 = (us16*)alloc((size_t)N*128*2);
  us16* B3 = (us16*)alloc((size_t)N*128*2);
  uint2* csr = (uint2*)alloc((size_t)E*8);
  float* disA=(float*)alloc((size_t)2*N*4);
  int* cnt =(int*)alloc((size_t)2*N*4);
  int* rp  =(int*)alloc((size_t)2*N*4);
  int* bsum=(int*)alloc(4096);
  float* c64=(float*)alloc(256);
  us16* wt =(us16*)alloc((size_t)102400*2);
  int* eofs = (int*)B0;          // E*4 = 6.4MB <= B0's 25.6MB; B0 first written after fill
  us16* Z1 = B0;
  us16* Z2 = B1;

  const int* srcp = ei;
  const int* dstp = ei + E;

  // ---- graph preprocessing: count(+rank) -> scan -> fill(raw w, no atomic) -> deg ----
  int M = 2*N;
  k_init<<<(M+255)/256,256,0,stream>>>(cnt,M);
  k_cnt<<<(E+255)/256,256,0,stream>>>(dstp,et,cnt,eofs,E);
  int SB = (M+2047)/2048;
  k_scan_reduce<<<SB,256,0,stream>>>(cnt,bsum,M);
  k_scan_top<<<1,64,0,stream>>>(bsum,SB);
  k_scan_apply<<<SB,256,0,stream>>>(cnt,bsum,rp,M);
  k_edge_fill<<<(E+255)/256,256,0,stream>>>(srcp,dstp,et,ew,rp,eofs,csr,E);
  k_deg_csr<<<(M+255)/256,256,0,stream>>>(csr,rp,cnt,disA,M);

  // ---- weight prep ----
  dim3 pg(64,7);
  k_prepw<<<pg,256,0,stream>>>(ft_w,g0_w,g1_w,p_w1,p_w2,wt);

  const us16* wt_ft = wt;
  const us16* wt_g00= wt+16384;
  const us16* wt_g01= wt+32768;
  const us16* wt_g10= wt+49152;
  const us16* wt_g11= wt+65536;
  const us16* wt_p1 = wt+81920;
  const us16* wt_p2 = wt+98304;
  const float* dis0 = disA;
  const float* dis1 = disA + N;

  int GB = (N+127)/128;
  int AB = (N+7)/8;
  // ---- feature transform: B0 = relu(x@ft_w + ft_b), f32 x staged directly ----
  k_mgemm<128,float><<<GB,256,0,stream>>>(x,x,128, wt_ft, ft_b, nullptr, nullptr, B0,128, N,128,1);
  // ---- both blocks' layer-0 linear, dis-scaled: T' = (h@W)*dis ----
  k_mgemm<128,us16><<<GB,256,0,stream>>>(B0,B0,128, wt_g00, nullptr,nullptr, dis0, B1,128, N,128,0);
  k_mgemm<128,us16><<<GB,256,0,stream>>>(B0,B0,128, wt_g10, nullptr,nullptr, dis1, B2,128, N,128,0);
  // ---- block 0 ----
  k_agg<<<AB,256,0,stream>>>(B1,csr,rp,cnt,0,dis0,
                             g0_b,g0_g,g0_be,g0_rm,g0_rv, nullptr, B0,1,N);      // h0 -> B0
  k_mgemm<128,us16><<<GB,256,0,stream>>>(B0,B0,128, wt_g01, nullptr,nullptr, dis0, B1,128, N,128,0);
  k_agg<<<AB,256,0,stream>>>(B1,csr,rp,cnt,0,dis0,
                             g0_b+128,g0_g+128,g0_be+128,g0_rm+128,g0_rv+128, B0, B3,0,N); // x0 -> B3
  // ---- block 1 ----
  k_agg<<<AB,256,0,stream>>>(B2,csr,rp,cnt,N,dis1,
                             g1_b,g1_g,g1_be,g1_rm,g1_rv, nullptr, B0,1,N);      // h1 -> B0
  k_mgemm<128,us16><<<GB,256,0,stream>>>(B0,B0,128, wt_g11, nullptr,nullptr, dis1, B1,128, N,128,0);
  k_agg<<<AB,256,0,stream>>>(B1,csr,rp,cnt,N,dis1,
                             g1_b+128,g1_g+128,g1_be+128,g1_rm+128,g1_rv+128, B0, B2,0,N); // x1 -> B2
  // ---- predictor ----
  k_const64<<<1,64,0,stream>>>(B3,B2,seed,p_w1,p_b1,c64);
  k_mgemm<64,us16><<<GB,256,0,stream>>>(B3,B2,128, wt_p1, nullptr, c64, nullptr, Z1,64, N,256,1);
  k_mgemm<64,us16><<<GB,256,0,stream>>>(Z1,Z1,64,  wt_p2, p_b2, nullptr, nullptr, Z2,64, N,64,1);
  k_outdot<<<(N+255)/256,256,0,stream>>>(Z2,p_w3,p_b3,out,N);
}

// Round 13
// 437.529 us; speedup vs baseline: 1.2232x; 1.0170x over previous
//
#include <hip/hip_runtime.h>
#include <hip/hip_bf16.h>
#include <stdint.h>

#define N_NODES 100000

typedef unsigned short us16;
typedef short bf16x8 __attribute__((ext_vector_type(8)));
typedef float f32x4 __attribute__((ext_vector_type(4)));

__device__ __forceinline__ float us2f(us16 u){
  union{ unsigned int i; float f; } x; x.i = ((unsigned int)u) << 16; return x.f;
}
__device__ __forceinline__ us16 f2us(float f){
  union{ float f; unsigned int i; } x; x.f = f;
  unsigned int i = x.i;
  unsigned int r = (i + 0x7FFFu + ((i >> 16) & 1u)) >> 16;
  return (us16)r;
}

// ---------------- init: zero cnt ----------------
__global__ __launch_bounds__(256) void k_init(int* __restrict__ cnt, int n2){
  int i = blockIdx.x*256 + threadIdx.x;
  if (i < n2) cnt[i]=0;
}

// ---------------- exclusive scan over M elements (R1-exact) ----------------
__global__ __launch_bounds__(256) void k_scan_reduce(const int* __restrict__ in, int* __restrict__ bsum, int M){
  __shared__ int sd[256];
  int base = blockIdx.x*2048; int t = threadIdx.x;
  int sum = 0;
  #pragma unroll
  for(int i=0;i<8;i++){ int p = base + t*8 + i; if(p<M) sum += in[p]; }
  sd[t]=sum; __syncthreads();
  for(int s=128;s>0;s>>=1){ if(t<s) sd[t]+=sd[t+s]; __syncthreads(); }
  if(t==0) bsum[blockIdx.x]=sd[0];
}
__global__ void k_scan_top(int* __restrict__ bsum, int B){
  if (threadIdx.x==0){ int run=0; for(int i=0;i<B;i++){ int v=bsum[i]; bsum[i]=run; run+=v; } }
}
__global__ __launch_bounds__(256) void k_scan_apply(const int* __restrict__ in, const int* __restrict__ bsum,
                                                    int* __restrict__ out, int M){
  __shared__ int sd[256];
  int base = blockIdx.x*2048; int t = threadIdx.x;
  int loc[8]; int sum=0;
  #pragma unroll
  for(int i=0;i<8;i++){ int p = base + t*8 + i; int v = (p<M)?in[p]:0; loc[i]=sum; sum+=v; }
  sd[t]=sum; __syncthreads();
  for(int ofs=1;ofs<256;ofs<<=1){
    int v = (t>=ofs)? sd[t-ofs] : 0;
    __syncthreads();
    sd[t]+=v;
    __syncthreads();
  }
  int excl = ((t==0)?0:sd[t-1]) + bsum[blockIdx.x];
  #pragma unroll
  for(int i=0;i<8;i++){ int p = base + t*8 + i; if(p<M) out[p]=excl+loc[i]; }
}

// ---------------- degree from CSR (sequential, atomic-free) ----------------
__global__ __launch_bounds__(256) void k_deg_csr(const uint2* __restrict__ csr,
                                                 const int* __restrict__ rp, const int* __restrict__ cnt,
                                                 float* __restrict__ disA, int M){
  int i = blockIdx.x*256+threadIdx.x;
  if(i>=M) return;
  int e0 = rp[i], c = cnt[i];
  float s = 1.0f;
  for(int e=e0; e<e0+c; e++) s += __uint_as_float(csr[e].y);
  disA[i] = rsqrtf(s);
}

// ---------------- fold dis[src] into coefficients (R8-proven): coef = w * dis[s] ----------------
__global__ __launch_bounds__(256) void k_coef(uint2* __restrict__ csr,
                                              const int* __restrict__ rp,
                                              const float* __restrict__ disA, int E){
  int e = blockIdx.x*256+threadIdx.x;
  if(e>=E) return;
  int rpN = rp[N_NODES];               // boundary: first type-1 entry
  int t = (e >= rpN) ? 1 : 0;
  uint2 q = csr[e];
  float w = __uint_as_float(q.y) * disA[t*N_NODES + (int)q.x];
  csr[e] = make_uint2(q.x, __float_as_uint(w));
}

// ---------------- weight prep: f32 [K][NC] -> bf16 transposed [NC][K] ----------------
__global__ __launch_bounds__(256) void k_prepw(const float* __restrict__ ft_w,
                                               const float* __restrict__ g0_w, const float* __restrict__ g1_w,
                                               const float* __restrict__ p_w1, const float* __restrict__ p_w2,
                                               us16* __restrict__ wt){
  int m = blockIdx.y;
  const float* srcp; int K, NCc; us16* dstp;
  switch(m){
    case 0: srcp=ft_w;        K=128; NCc=128; dstp=wt;        break;
    case 1: srcp=g0_w;        K=128; NCc=128; dstp=wt+16384;  break;
    case 2: srcp=g0_w+16384;  K=128; NCc=128; dstp=wt+32768;  break;
    case 3: srcp=g1_w;        K=128; NCc=128; dstp=wt+49152;  break;
    case 4: srcp=g1_w+16384;  K=128; NCc=128; dstp=wt+65536;  break;
    case 5: srcp=p_w1;        K=256; NCc=64;  dstp=wt+81920;  break;
    default:srcp=p_w2;        K=64;  NCc=64;  dstp=wt+98304;  break;
  }
  int idx = blockIdx.x*256+threadIdx.x;
  if(idx >= K*NCc) return;
  int nn = idx / K, k = idx - nn*K;
  dstp[idx] = f2us(srcp[(size_t)k*NCc + nn]);
}

// ---------- MFMA GEMM body (R6-verified core): C[n,NC](bf16) = A@W (+bias/addv, relu) ----------
template<int NC, typename AT>
__device__ __forceinline__ void mgemm_body(int bid,
                 const AT* __restrict__ A0, const AT* __restrict__ A1,
                 int lda, const us16* __restrict__ Wt,
                 const float* __restrict__ bias, const float* __restrict__ addv,
                 us16* __restrict__ C, int ldc, int n, int KC, int relu,
                 us16* Alds, us16* Wlds){
  constexpr int NB = NC/16;
  const int tid = threadIdx.x;
  const int lane = tid & 63, wid = tid >> 6;
  const int rowBase = bid*128;
  f32x4 zero = {0.f,0.f,0.f,0.f};
  f32x4 acc[2][NB];
  #pragma unroll
  for(int m=0;m<2;m++)
    #pragma unroll
    for(int nb=0;nb<NB;nb++) acc[m][nb] = zero;

  for(int kk=0; kk<KC; kk+=64){
    const AT* Ab = (kk<128)? A0 : A1;
    const int kc = (kk<128)? kk : (kk-128);
    #pragma unroll
    for(int p=0;p<4;p++){
      int idx = p*256 + tid;
      int r = idx>>3, u = idx&7;
      int row = rowBase + r;
      uint4 v = make_uint4(0u,0u,0u,0u);
      if(row<n){
        if constexpr (sizeof(AT)==2){
          v = *(const uint4*)(Ab + (size_t)row*lda + kc + u*8);
        } else {
          float4 f0 = *(const float4*)(Ab + (size_t)row*lda + kc + u*8);
          float4 f1 = *(const float4*)(Ab + (size_t)row*lda + kc + u*8 + 4);
          us16 tmp[8] = {f2us(f0.x),f2us(f0.y),f2us(f0.z),f2us(f0.w),
                         f2us(f1.x),f2us(f1.y),f2us(f1.z),f2us(f1.w)};
          v = *(const uint4*)tmp;
        }
      }
      *(uint4*)&Alds[(r*8 + (u ^ (r&7)))*8] = v;
    }
    #pragma unroll
    for(int p=0;p<NB/2;p++){
      int idx = p*256 + tid;
      int cI = idx>>3, u = idx&7;
      uint4 v = *(const uint4*)(Wt + (size_t)cI*KC + kk + u*8);
      *(uint4*)&Wlds[(cI*8 + (u ^ (cI&7)))*8] = v;
    }
    __syncthreads();
    #pragma unroll
    for(int ks=0;ks<2;ks++){
      bf16x8 af[2];
      #pragma unroll
      for(int m=0;m<2;m++){
        int r = wid*32 + m*16 + (lane&15);
        int u = (ks*4 + (lane>>4)) ^ (r&7);
        af[m] = *(const bf16x8*)&Alds[(r*8+u)*8];
      }
      #pragma unroll
      for(int nb=0;nb<NB;nb++){
        int c2 = nb*16 + (lane&15);
        int u = (ks*4 + (lane>>4)) ^ (c2&7);
        bf16x8 bfv = *(const bf16x8*)&Wlds[(c2*8+u)*8];
        #pragma unroll
        for(int m=0;m<2;m++)
          acc[m][nb] = __builtin_amdgcn_mfma_f32_16x16x32_bf16(af[m], bfv, acc[m][nb], 0,0,0);
      }
    }
    __syncthreads();
  }
  #pragma unroll
  for(int nb=0;nb<NB;nb++){
    int col = nb*16 + (lane&15);
    float badd = (bias? bias[col]:0.f) + (addv? addv[col]:0.f);
    #pragma unroll
    for(int m=0;m<2;m++){
      #pragma unroll
      for(int j=0;j<4;j++){
        int row = rowBase + wid*32 + m*16 + (lane>>4)*4 + j;
        if(row<n){
          float v = acc[m][nb][j] + badd;
          if(relu) v = fmaxf(v,0.f);
          C[(size_t)row*ldc + col] = f2us(v);
        }
      }
    }
  }
}

// standalone GEMM kernel
template<int NC, typename AT>
__global__ __launch_bounds__(256) void k_mgemm(const AT* __restrict__ A0, const AT* __restrict__ A1,
                 int lda, const us16* __restrict__ Wt,
                 const float* __restrict__ bias, const float* __restrict__ addv,
                 us16* __restrict__ C, int ldc, int n, int KC, int relu){
  __shared__ us16 smem[128*64 + NC*64];
  mgemm_body<NC,AT>(blockIdx.x, A0,A1,lda, Wt, bias,addv, C,ldc, n,KC,relu, smem, smem+128*64);
}

// ---- FUSED K1: [cnt blocks | ft-GEMM blocks] (independent chains overlap) ----
__global__ __launch_bounds__(256) void k_cnt_ft(const int* __restrict__ dst, const int* __restrict__ et,
    int* __restrict__ cnt, int* __restrict__ eofs, int E, int CB,
    const float* __restrict__ x, const us16* __restrict__ wt_ft, const float* __restrict__ ft_b,
    us16* __restrict__ B0, int n){
  __shared__ us16 smem[128*64 + 128*64];
  int b = blockIdx.x;
  if (b < CB){
    int e = b*256 + threadIdx.x;
    if (e < E){
      int d = dst[e]; int t = et[e];
      eofs[e] = atomicAdd(&cnt[t*N_NODES + d], 1);
    }
  } else {
    mgemm_body<128,float>(b - CB, x, x, 128, wt_ft, ft_b, nullptr, B0, 128, n, 128, 1,
                          smem, smem + 128*64);
  }
}

// ---- FUSED K3: [fill blocks | g00-GEMM blocks | g10-GEMM blocks] ----
__global__ __launch_bounds__(256) void k_fill_l0(
    const int* __restrict__ src, const int* __restrict__ dst,
    const int* __restrict__ et, const float* __restrict__ ew,
    const int* __restrict__ rp, const int* __restrict__ eofs,
    uint2* __restrict__ csr, int E, int FB, int GB,
    const us16* __restrict__ B0,
    const us16* __restrict__ wt_g00, const us16* __restrict__ wt_g10,
    us16* __restrict__ B1, us16* __restrict__ B2, int n){
  __shared__ us16 smem[128*64 + 128*64];
  int b = blockIdx.x;
  if (b < FB){
    int e = b*256 + threadIdx.x;
    if (e < E){
      int s=src[e], d=dst[e], t=et[e]; float w=ew[e];
      int idx = t*N_NODES + d;
      int pos = rp[idx] + eofs[e];
      csr[pos] = make_uint2((unsigned)s, __float_as_uint(w));
    }
  } else if (b < FB + GB){
    mgemm_body<128,us16>(b - FB, B0, B0, 128, wt_g00, nullptr, nullptr, B1, 128, n, 128, 0,
                         smem, smem + 128*64);
  } else {
    mgemm_body<128,us16>(b - FB - GB, B0, B0, 128, wt_g10, nullptr, nullptr, B2, 128, n, 128, 0,
                         smem, smem + 128*64);
  }
}

// --- aggregation: 2 rows/wave, chunk-4, 8B gathers (R12 structure, R9 math) ---
// coef in csr = w*dis_s; out = acc*dis_r + T[r]*invdeg + bias, BN, relu/resid.
__global__ __launch_bounds__(256) void k_agg(const us16* __restrict__ T,
  const uint2* __restrict__ csr,
  const int* __restrict__ rp, const int* __restrict__ cnt, int rowOfs,
  const float* __restrict__ dis,
  const float* __restrict__ bias, const float* __restrict__ gamma, const float* __restrict__ beta,
  const float* __restrict__ rm, const float* __restrict__ rv,
  const us16* __restrict__ resid,
  us16* __restrict__ out, int relu, int n){
  const int wid = threadIdx.x >> 6, lane = threadIdx.x & 63;
  const int hw = lane >> 5;        // half-wave index: which row
  const int sl = lane & 31;        // sublane within half
  int r = blockIdx.x*8 + wid*2 + hw;
  if (r >= n) return;
  const int c0 = sl*4;             // 4 bf16 cols = 8B
  int idx = rowOfs + r;
  int e0 = rp[idx];
  int ec = cnt[idx];
  const uint2* cp = csr + e0;
  float a0=0.f, a1=0.f, a2=0.f, a3=0.f;
  int nchunk = ec >> 2;
  int rem = ec & 3;
  for(int ch=0; ch<nchunk; ch++){
    uint2 q0 = cp[0], q1 = cp[1], q2 = cp[2], q3 = cp[3];
    cp += 4;
    uint2 va = *(const uint2*)(T + (size_t)q0.x*128 + c0);
    uint2 vb = *(const uint2*)(T + (size_t)q1.x*128 + c0);
    uint2 vc = *(const uint2*)(T + (size_t)q2.x*128 + c0);
    uint2 vd = *(const uint2*)(T + (size_t)q3.x*128 + c0);
    float ca = __uint_as_float(q0.y), cb = __uint_as_float(q1.y);
    float cc = __uint_as_float(q2.y), cd = __uint_as_float(q3.y);
    a0 += ca*us2f((us16)(va.x & 0xffffu));
    a1 += ca*us2f((us16)(va.x >> 16));
    a2 += ca*us2f((us16)(va.y & 0xffffu));
    a3 += ca*us2f((us16)(va.y >> 16));
    a0 += cb*us2f((us16)(vb.x & 0xffffu));
    a1 += cb*us2f((us16)(vb.x >> 16));
    a2 += cb*us2f((us16)(vb.y & 0xffffu));
    a3 += cb*us2f((us16)(vb.y >> 16));
    a0 += cc*us2f((us16)(vc.x & 0xffffu));
    a1 += cc*us2f((us16)(vc.x >> 16));
    a2 += cc*us2f((us16)(vc.y & 0xffffu));
    a3 += cc*us2f((us16)(vc.y >> 16));
    a0 += cd*us2f((us16)(vd.x & 0xffffu));
    a1 += cd*us2f((us16)(vd.x >> 16));
    a2 += cd*us2f((us16)(vd.y & 0xffffu));
    a3 += cd*us2f((us16)(vd.y >> 16));
  }
  for(int i=0;i<rem;i++){
    uint2 q = cp[i];
    float c = __uint_as_float(q.y);
    uint2 v = *(const uint2*)(T + (size_t)q.x*128 + c0);
    a0 += c*us2f((us16)(v.x & 0xffffu));
    a1 += c*us2f((us16)(v.x >> 16));
    a2 += c*us2f((us16)(v.y & 0xffffu));
    a3 += c*us2f((us16)(v.y >> 16));
  }
  float disr = dis[r]; float invdeg = disr*disr;
  uint2 vs = *(const uint2*)(T + (size_t)r*128 + c0);
  float4 bi = *(const float4*)(bias + c0);
  float4 ga = *(const float4*)(gamma + c0);
  float4 be = *(const float4*)(beta + c0);
  float4 rmv= *(const float4*)(rm + c0);
  float4 rvv= *(const float4*)(rv + c0);
  float o0 = a0*disr + us2f((us16)(vs.x & 0xffffu))*invdeg + bi.x;
  float o1 = a1*disr + us2f((us16)(vs.x >> 16))*invdeg + bi.y;
  float o2 = a2*disr + us2f((us16)(vs.y & 0xffffu))*invdeg + bi.z;
  float o3 = a3*disr + us2f((us16)(vs.y >> 16))*invdeg + bi.w;
  o0 = (o0 - rmv.x)*(ga.x*rsqrtf(rvv.x + 1e-5f)) + be.x;
  o1 = (o1 - rmv.y)*(ga.y*rsqrtf(rvv.y + 1e-5f)) + be.y;
  o2 = (o2 - rmv.z)*(ga.z*rsqrtf(rvv.z + 1e-5f)) + be.z;
  o3 = (o3 - rmv.w)*(ga.w*rsqrtf(rvv.w + 1e-5f)) + be.w;
  if (relu){
    o0=fmaxf(o0,0.f); o1=fmaxf(o1,0.f); o2=fmaxf(o2,0.f); o3=fmaxf(o3,0.f);
  }
  if (resid){
    uint2 vr = *(const uint2*)(resid + (size_t)r*128 + c0);
    o0 += us2f((us16)(vr.x & 0xffffu));
    o1 += us2f((us16)(vr.x >> 16));
    o2 += us2f((us16)(vr.y & 0xffffu));
    o3 += us2f((us16)(vr.y >> 16));
  }
  uint2 up;
  up.x = (unsigned)f2us(o0) | ((unsigned)f2us(o1) << 16);
  up.y = (unsigned)f2us(o2) | ((unsigned)f2us(o3) << 16);
  *(uint2*)(out + (size_t)r*128 + c0) = up;
}

// ------------- seed constant (R12-exact) -------------
__global__ void k_const64(const us16* __restrict__ X0, const us16* __restrict__ X1,
                          const int* __restrict__ seed,
                          const float* __restrict__ pw1, const float* __restrict__ pb1,
                          float* __restrict__ c64){
  int j = threadIdx.x;  // 64 threads
  int s = seed[0];
  const us16* x0 = X0 + (size_t)s*128;
  const us16* x1 = X1 + (size_t)s*128;
  float acc = pb1[j];
  #pragma unroll 8
  for(int k=0;k<128;k++) acc += us2f(x0[k]) * pw1[(256+k)*64 + j];
  #pragma unroll 8
  for(int k=0;k<128;k++) acc += us2f(x1[k]) * pw1[(384+k)*64 + j];
  c64[j]=acc;
}

// ------------- final dot (R12-exact) -------------
__global__ __launch_bounds__(256) void k_outdot(const us16* __restrict__ Z2, const float* __restrict__ w3,
                                                const float* __restrict__ b3, float* __restrict__ out, int n){
  int r = blockIdx.x*256 + threadIdx.x;
  if(r>=n) return;
  const us16* z = Z2 + (size_t)r*64;
  float acc = b3[0];
  #pragma unroll 8
  for(int j=0;j<64;j++) acc += us2f(z[j])*w3[j];
  out[r]=acc;
}

extern "C" void kernel_launch(void* const* d_in, const int* in_sizes, int n_in,
                              void* d_out, int out_size, void* d_ws, size_t ws_size,
                              hipStream_t stream){
  const int N = N_NODES;
  const int E = in_sizes[2];
  const float* x   = (const float*)d_in[0];
  const int*   ei  = (const int*)d_in[1];
  const int*   et  = (const int*)d_in[2];
  const float* ew  = (const float*)d_in[3];
  const int*   seed= (const int*)d_in[4];
  const float* ft_w= (const float*)d_in[5];
  const float* ft_b= (const float*)d_in[6];
  const float* g0_w= (const float*)d_in[7];
  const float* g0_b= (const float*)d_in[8];
  const float* g0_g= (const float*)d_in[9];
  const float* g0_be=(const float*)d_in[10];
  const float* g0_rm=(const float*)d_in[11];
  const float* g0_rv=(const float*)d_in[12];
  const float* g1_w= (const float*)d_in[13];
  const float* g1_b= (const float*)d_in[14];
  const float* g1_g= (const float*)d_in[15];
  const float* g1_be=(const float*)d_in[16];
  const float* g1_rm=(const float*)d_in[17];
  const float* g1_rv=(const float*)d_in[18];
  const float* p_w1= (const float*)d_in[19];
  const float* p_b1= (const float*)d_in[20];
  const float* p_w2= (const float*)d_in[21];
  const float* p_b2= (const float*)d_in[22];
  const float* p_w3= (const float*)d_in[23];
  const float* p_b3= (const float*)d_in[24];
  float* out = (float*)d_out;

  // Footprint ~117.8 MB (< proven 119.2 MB). eofs aliases B3 (first feature write to B3 is x0, long after fill).
  char* wsp = (char*)d_ws;
  auto alloc = [&](size_t bytes)->char*{ char* p = wsp; wsp += (bytes + 255) & ~(size_t)255; return p; };
  us16* B0 = (us16*)alloc((size_t)N*128*2);
  us16* B1 = (us16*)alloc((size_t)N*128*2);
  us16* B2 = (us16*)alloc((size_t)N*128*2);
  us16* B3 = (us16*)alloc((size_t)N*128*2);
  uint2* csr = (uint2*)alloc((size_t)E*8);
  float* disA=(float*)alloc((size_t)2*N*4);
  int* cnt =(int*)alloc((size_t)2*N*4);
  int* rp  =(int*)alloc((size_t)2*N*4);
  int* bsum=(int*)alloc(4096);
  float* c64=(float*)alloc(256);
  us16* wt =(us16*)alloc((size_t)102400*2);
  int* eofs = (int*)B3;          // E*4 = 6.4MB <= B3's 25.6MB; B3 first written at x0 (after fill)
  us16* Z1 = B0;
  us16* Z2 = B1;

  const int* srcp = ei;
  const int* dstp = ei + E;

  int M = 2*N;
  int CB = (E+255)/256;
  int GB = (N+127)/128;
  int AB = (N+7)/8;
  int SB = (M+2047)/2048;

  // ---- prep: zero counters; bf16 weights ----
  k_init<<<(M+255)/256,256,0,stream>>>(cnt,M);
  dim3 pg(64,7);
  k_prepw<<<pg,256,0,stream>>>(ft_w,g0_w,g1_w,p_w1,p_w2,wt);

  const us16* wt_ft = wt;
  const us16* wt_g00= wt+16384;
  const us16* wt_g01= wt+32768;
  const us16* wt_g10= wt+49152;
  const us16* wt_g11= wt+65536;
  const us16* wt_p1 = wt+81920;
  const us16* wt_p2 = wt+98304;
  const float* dis0 = disA;
  const float* dis1 = disA + N;

  // ---- K1: fused [cnt | ft-GEMM] ----
  k_cnt_ft<<<CB+GB,256,0,stream>>>(dstp,et,cnt,eofs,E,CB, x,wt_ft,ft_b,B0,N);
  // ---- scans: rp ----
  k_scan_reduce<<<SB,256,0,stream>>>(cnt,bsum,M);
  k_scan_top<<<1,64,0,stream>>>(bsum,SB);
  k_scan_apply<<<SB,256,0,stream>>>(cnt,bsum,rp,M);
  // ---- K3: fused [fill | g00 | g10] ----
  k_fill_l0<<<CB+2*GB,256,0,stream>>>(srcp,dstp,et,ew,rp,eofs,csr,E,CB,GB,
                                      B0,wt_g00,wt_g10,B1,B2,N);
  // ---- deg + coef ----
  k_deg_csr<<<(M+255)/256,256,0,stream>>>(csr,rp,cnt,disA,M);
  k_coef<<<(E+255)/256,256,0,stream>>>(csr,rp,disA,E);

  // ---- block 0 ----
  k_agg<<<AB,256,0,stream>>>(B1,csr,rp,cnt,0,dis0,
                             g0_b,g0_g,g0_be,g0_rm,g0_rv, nullptr, B0,1,N);      // h0 -> B0
  k_mgemm<128,us16><<<GB,256,0,stream>>>(B0,B0,128, wt_g01, nullptr,nullptr, B1,128, N,128,0);
  k_agg<<<AB,256,0,stream>>>(B1,csr,rp,cnt,0,dis0,
                             g0_b+128,g0_g+128,g0_be+128,g0_rm+128,g0_rv+128, B0, B3,0,N); // x0 -> B3
  // ---- block 1 ----
  k_agg<<<AB,256,0,stream>>>(B2,csr,rp,cnt,N,dis1,
                             g1_b,g1_g,g1_be,g1_rm,g1_rv, nullptr, B0,1,N);      // h1 -> B0
  k_mgemm<128,us16><<<GB,256,0,stream>>>(B0,B0,128, wt_g11, nullptr,nullptr, B1,128, N,128,0);
  k_agg<<<AB,256,0,stream>>>(B1,csr,rp,cnt,N,dis1,
                             g1_b+128,g1_g+128,g1_be+128,g1_rm+128,g1_rv+128, B0, B2,0,N); // x1 -> B2
  // ---- predictor ----
  k_const64<<<1,64,0,stream>>>(B3,B2,seed,p_w1,p_b1,c64);
  k_mgemm<64,us16><<<GB,256,0,stream>>>(B3,B2,128, wt_p1, nullptr, c64, Z1,64, N,256,1);
  k_mgemm<64,us16><<<GB,256,0,stream>>>(Z1,Z1,64,  wt_p2, p_b2, nullptr, Z2,64, N,64,1);
  k_outdot<<<(N+255)/256,256,0,stream>>>(Z2,p_w3,p_b3,out,N);
}

// Round 14
// 413.171 us; speedup vs baseline: 1.2953x; 1.0590x over previous
//
#include <hip/hip_runtime.h>
#include <hip/hip_bf16.h>
#include <stdint.h>

#define N_NODES 100000

typedef unsigned short us16;
typedef short bf16x8 __attribute__((ext_vector_type(8)));
typedef float f32x4 __attribute__((ext_vector_type(4)));

__device__ __forceinline__ float us2f(us16 u){
  union{ unsigned int i; float f; } x; x.i = ((unsigned int)u) << 16; return x.f;
}
__device__ __forceinline__ us16 f2us(float f){
  union{ float f; unsigned int i; } x; x.f = f;
  unsigned int i = x.i;
  unsigned int r = (i + 0x7FFFu + ((i >> 16) & 1u)) >> 16;
  return (us16)r;
}

// ---------------- init: zero cnt ----------------
__global__ __launch_bounds__(256) void k_init(int* __restrict__ cnt, int n2){
  int i = blockIdx.x*256 + threadIdx.x;
  if (i < n2) cnt[i]=0;
}

// ------- per-(type,dst) counts: standalone (atomics need full occupancy — R13 lesson) -------
__global__ __launch_bounds__(256) void k_cnt(const int* __restrict__ dst,
                                             const int* __restrict__ et,
                                             int* __restrict__ cnt,
                                             int* __restrict__ eofs, int E){
  int e = blockIdx.x*256 + threadIdx.x;
  if (e>=E) return;
  int d = dst[e]; int t = et[e];
  eofs[e] = atomicAdd(&cnt[t*N_NODES + d], 1);
}

// ---------------- exclusive scan over M elements (R1-exact) ----------------
__global__ __launch_bounds__(256) void k_scan_reduce(const int* __restrict__ in, int* __restrict__ bsum, int M){
  __shared__ int sd[256];
  int base = blockIdx.x*2048; int t = threadIdx.x;
  int sum = 0;
  #pragma unroll
  for(int i=0;i<8;i++){ int p = base + t*8 + i; if(p<M) sum += in[p]; }
  sd[t]=sum; __syncthreads();
  for(int s=128;s>0;s>>=1){ if(t<s) sd[t]+=sd[t+s]; __syncthreads(); }
  if(t==0) bsum[blockIdx.x]=sd[0];
}
__global__ void k_scan_top(int* __restrict__ bsum, int B){
  if (threadIdx.x==0){ int run=0; for(int i=0;i<B;i++){ int v=bsum[i]; bsum[i]=run; run+=v; } }
}
__global__ __launch_bounds__(256) void k_scan_apply(const int* __restrict__ in, const int* __restrict__ bsum,
                                                    int* __restrict__ out, int M){
  __shared__ int sd[256];
  int base = blockIdx.x*2048; int t = threadIdx.x;
  int loc[8]; int sum=0;
  #pragma unroll
  for(int i=0;i<8;i++){ int p = base + t*8 + i; int v = (p<M)?in[p]:0; loc[i]=sum; sum+=v; }
  sd[t]=sum; __syncthreads();
  for(int ofs=1;ofs<256;ofs<<=1){
    int v = (t>=ofs)? sd[t-ofs] : 0;
    __syncthreads();
    sd[t]+=v;
    __syncthreads();
  }
  int excl = ((t==0)?0:sd[t-1]) + bsum[blockIdx.x];
  #pragma unroll
  for(int i=0;i<8;i++){ int p = base + t*8 + i; if(p<M) out[p]=excl+loc[i]; }
}

// ---------------- fold dis[src] into coefficients (R8-proven): coef = w * dis[s] ----------------
__global__ __launch_bounds__(256) void k_coef(uint2* __restrict__ csr,
                                              const int* __restrict__ rp,
                                              const float* __restrict__ disA, int E){
  int e = blockIdx.x*256+threadIdx.x;
  if(e>=E) return;
  int rpN = rp[N_NODES];               // boundary: first type-1 entry
  int t = (e >= rpN) ? 1 : 0;
  uint2 q = csr[e];
  float w = __uint_as_float(q.y) * disA[t*N_NODES + (int)q.x];
  csr[e] = make_uint2(q.x, __float_as_uint(w));
}

// ---------------- weight prep: f32 [K][NC] -> bf16 transposed [NC][K] ----------------
__global__ __launch_bounds__(256) void k_prepw(const float* __restrict__ ft_w,
                                               const float* __restrict__ g0_w, const float* __restrict__ g1_w,
                                               const float* __restrict__ p_w1, const float* __restrict__ p_w2,
                                               us16* __restrict__ wt){
  int m = blockIdx.y;
  const float* srcp; int K, NCc; us16* dstp;
  switch(m){
    case 0: srcp=ft_w;        K=128; NCc=128; dstp=wt;        break;
    case 1: srcp=g0_w;        K=128; NCc=128; dstp=wt+16384;  break;
    case 2: srcp=g0_w+16384;  K=128; NCc=128; dstp=wt+32768;  break;
    case 3: srcp=g1_w;        K=128; NCc=128; dstp=wt+49152;  break;
    case 4: srcp=g1_w+16384;  K=128; NCc=128; dstp=wt+65536;  break;
    case 5: srcp=p_w1;        K=256; NCc=64;  dstp=wt+81920;  break;
    default:srcp=p_w2;        K=64;  NCc=64;  dstp=wt+98304;  break;
  }
  int idx = blockIdx.x*256+threadIdx.x;
  if(idx >= K*NCc) return;
  int nn = idx / K, k = idx - nn*K;
  dstp[idx] = f2us(srcp[(size_t)k*NCc + nn]);
}

// ---------- MFMA GEMM body (R6-verified core): C[n,NC](bf16) = A@W (+bias/addv, relu) ----------
template<int NC, typename AT>
__device__ __forceinline__ void mgemm_body(int bid,
                 const AT* __restrict__ A0, const AT* __restrict__ A1,
                 int lda, const us16* __restrict__ Wt,
                 const float* __restrict__ bias, const float* __restrict__ addv,
                 us16* __restrict__ C, int ldc, int n, int KC, int relu,
                 us16* Alds, us16* Wlds){
  constexpr int NB = NC/16;
  const int tid = threadIdx.x;
  const int lane = tid & 63, wid = tid >> 6;
  const int rowBase = bid*128;
  f32x4 zero = {0.f,0.f,0.f,0.f};
  f32x4 acc[2][NB];
  #pragma unroll
  for(int m=0;m<2;m++)
    #pragma unroll
    for(int nb=0;nb<NB;nb++) acc[m][nb] = zero;

  for(int kk=0; kk<KC; kk+=64){
    const AT* Ab = (kk<128)? A0 : A1;
    const int kc = (kk<128)? kk : (kk-128);
    #pragma unroll
    for(int p=0;p<4;p++){
      int idx = p*256 + tid;
      int r = idx>>3, u = idx&7;
      int row = rowBase + r;
      uint4 v = make_uint4(0u,0u,0u,0u);
      if(row<n){
        if constexpr (sizeof(AT)==2){
          v = *(const uint4*)(Ab + (size_t)row*lda + kc + u*8);
        } else {
          float4 f0 = *(const float4*)(Ab + (size_t)row*lda + kc + u*8);
          float4 f1 = *(const float4*)(Ab + (size_t)row*lda + kc + u*8 + 4);
          us16 tmp[8] = {f2us(f0.x),f2us(f0.y),f2us(f0.z),f2us(f0.w),
                         f2us(f1.x),f2us(f1.y),f2us(f1.z),f2us(f1.w)};
          v = *(const uint4*)tmp;
        }
      }
      *(uint4*)&Alds[(r*8 + (u ^ (r&7)))*8] = v;
    }
    #pragma unroll
    for(int p=0;p<NB/2;p++){
      int idx = p*256 + tid;
      int cI = idx>>3, u = idx&7;
      uint4 v = *(const uint4*)(Wt + (size_t)cI*KC + kk + u*8);
      *(uint4*)&Wlds[(cI*8 + (u ^ (cI&7)))*8] = v;
    }
    __syncthreads();
    #pragma unroll
    for(int ks=0;ks<2;ks++){
      bf16x8 af[2];
      #pragma unroll
      for(int m=0;m<2;m++){
        int r = wid*32 + m*16 + (lane&15);
        int u = (ks*4 + (lane>>4)) ^ (r&7);
        af[m] = *(const bf16x8*)&Alds[(r*8+u)*8];
      }
      #pragma unroll
      for(int nb=0;nb<NB;nb++){
        int c2 = nb*16 + (lane&15);
        int u = (ks*4 + (lane>>4)) ^ (c2&7);
        bf16x8 bfv = *(const bf16x8*)&Wlds[(c2*8+u)*8];
        #pragma unroll
        for(int m=0;m<2;m++)
          acc[m][nb] = __builtin_amdgcn_mfma_f32_16x16x32_bf16(af[m], bfv, acc[m][nb], 0,0,0);
      }
    }
    __syncthreads();
  }
  #pragma unroll
  for(int nb=0;nb<NB;nb++){
    int col = nb*16 + (lane&15);
    float badd = (bias? bias[col]:0.f) + (addv? addv[col]:0.f);
    #pragma unroll
    for(int m=0;m<2;m++){
      #pragma unroll
      for(int j=0;j<4;j++){
        int row = rowBase + wid*32 + m*16 + (lane>>4)*4 + j;
        if(row<n){
          float v = acc[m][nb][j] + badd;
          if(relu) v = fmaxf(v,0.f);
          C[(size_t)row*ldc + col] = f2us(v);
        }
      }
    }
  }
}

// standalone GEMM kernel (predictor)
template<int NC, typename AT>
__global__ __launch_bounds__(256) void k_mgemm(const AT* __restrict__ A0, const AT* __restrict__ A1,
                 int lda, const us16* __restrict__ Wt,
                 const float* __restrict__ bias, const float* __restrict__ addv,
                 us16* __restrict__ C, int ldc, int n, int KC, int relu){
  __shared__ us16 smem[128*64 + NC*64];
  mgemm_body<NC,AT>(blockIdx.x, A0,A1,lda, Wt, bias,addv, C,ldc, n,KC,relu, smem, smem+128*64);
}

// ---- FUSED: [fill | ft-GEMM] (scatter-store tolerates reduced occupancy — R13 lesson) ----
__global__ __launch_bounds__(256) void k_fill_ft(
    const int* __restrict__ src, const int* __restrict__ dst,
    const int* __restrict__ et, const float* __restrict__ ew,
    const int* __restrict__ rp, const int* __restrict__ eofs,
    uint2* __restrict__ csr, int E, int CB,
    const float* __restrict__ x, const us16* __restrict__ wt_ft, const float* __restrict__ ft_b,
    us16* __restrict__ B0, int n){
  __shared__ us16 smem[128*64 + 128*64];
  int b = blockIdx.x;
  if (b < CB){
    int e = b*256 + threadIdx.x;
    if (e < E){
      int s=src[e], d=dst[e], t=et[e]; float w=ew[e];
      int idx = t*N_NODES + d;
      int pos = rp[idx] + eofs[e];
      csr[pos] = make_uint2((unsigned)s, __float_as_uint(w));
    }
  } else {
    mgemm_body<128,float>(b - CB, x, x, 128, wt_ft, ft_b, nullptr, B0, 128, n, 128, 1,
                          smem, smem + 128*64);
  }
}

// ---- FUSED: [deg | g00 | g10] ----
__global__ __launch_bounds__(256) void k_deg_l0(
    const uint2* __restrict__ csr, const int* __restrict__ rp, const int* __restrict__ cnt,
    float* __restrict__ disA, int M, int DB, int GB,
    const us16* __restrict__ B0,
    const us16* __restrict__ wt_g00, const us16* __restrict__ wt_g10,
    us16* __restrict__ B1, us16* __restrict__ B2, int n){
  __shared__ us16 smem[128*64 + 128*64];
  int b = blockIdx.x;
  if (b < DB){
    int i = b*256 + threadIdx.x;
    if (i < M){
      int e0 = rp[i], c = cnt[i];
      float s = 1.0f;
      for(int e=e0; e<e0+c; e++) s += __uint_as_float(csr[e].y);
      disA[i] = rsqrtf(s);
    }
  } else if (b < DB + GB){
    mgemm_body<128,us16>(b - DB, B0, B0, 128, wt_g00, nullptr, nullptr, B1, 128, n, 128, 0,
                         smem, smem + 128*64);
  } else {
    mgemm_body<128,us16>(b - DB - GB, B0, B0, 128, wt_g10, nullptr, nullptr, B2, 128, n, 128, 0,
                         smem, smem + 128*64);
  }
}

// ---- FUSED: [gemmA | gemmB] (both 128-col, bf16 A) ----
__global__ __launch_bounds__(256) void k_gemm2(int GB,
    const us16* __restrict__ Aa, const us16* __restrict__ Wa, us16* __restrict__ Ca,
    const us16* __restrict__ Ab, const us16* __restrict__ Wb, us16* __restrict__ Cb, int n){
  __shared__ us16 smem[128*64 + 128*64];
  int b = blockIdx.x;
  if (b < GB)
    mgemm_body<128,us16>(b, Aa, Aa, 128, Wa, nullptr, nullptr, Ca, 128, n, 128, 0, smem, smem+128*64);
  else
    mgemm_body<128,us16>(b-GB, Ab, Ab, 128, Wb, nullptr, nullptr, Cb, 128, n, 128, 0, smem, smem+128*64);
}

// --- aggregation body (R12-proven): 2 rows/wave, chunk-4, 8B gathers ---
__device__ __forceinline__ void agg_body(int bid, const us16* __restrict__ T,
  const uint2* __restrict__ csr,
  const int* __restrict__ rp, const int* __restrict__ cnt, int rowOfs,
  const float* __restrict__ dis,
  const float* __restrict__ bias, const float* __restrict__ gamma, const float* __restrict__ beta,
  const float* __restrict__ rm, const float* __restrict__ rv,
  const us16* __restrict__ resid,
  us16* __restrict__ out, int relu, int n){
  const int wid = threadIdx.x >> 6, lane = threadIdx.x & 63;
  const int hw = lane >> 5;
  const int sl = lane & 31;
  int r = bid*8 + wid*2 + hw;
  if (r >= n) return;
  const int c0 = sl*4;
  int idx = rowOfs + r;
  int e0 = rp[idx];
  int ec = cnt[idx];
  const uint2* cp = csr + e0;
  float a0=0.f, a1=0.f, a2=0.f, a3=0.f;
  int nchunk = ec >> 2;
  int rem = ec & 3;
  for(int ch=0; ch<nchunk; ch++){
    uint2 q0 = cp[0], q1 = cp[1], q2 = cp[2], q3 = cp[3];
    cp += 4;
    uint2 va = *(const uint2*)(T + (size_t)q0.x*128 + c0);
    uint2 vb = *(const uint2*)(T + (size_t)q1.x*128 + c0);
    uint2 vc = *(const uint2*)(T + (size_t)q2.x*128 + c0);
    uint2 vd = *(const uint2*)(T + (size_t)q3.x*128 + c0);
    float ca = __uint_as_float(q0.y), cb = __uint_as_float(q1.y);
    float cc = __uint_as_float(q2.y), cd = __uint_as_float(q3.y);
    a0 += ca*us2f((us16)(va.x & 0xffffu));
    a1 += ca*us2f((us16)(va.x >> 16));
    a2 += ca*us2f((us16)(va.y & 0xffffu));
    a3 += ca*us2f((us16)(va.y >> 16));
    a0 += cb*us2f((us16)(vb.x & 0xffffu));
    a1 += cb*us2f((us16)(vb.x >> 16));
    a2 += cb*us2f((us16)(vb.y & 0xffffu));
    a3 += cb*us2f((us16)(vb.y >> 16));
    a0 += cc*us2f((us16)(vc.x & 0xffffu));
    a1 += cc*us2f((us16)(vc.x >> 16));
    a2 += cc*us2f((us16)(vc.y & 0xffffu));
    a3 += cc*us2f((us16)(vc.y >> 16));
    a0 += cd*us2f((us16)(vd.x & 0xffffu));
    a1 += cd*us2f((us16)(vd.x >> 16));
    a2 += cd*us2f((us16)(vd.y & 0xffffu));
    a3 += cd*us2f((us16)(vd.y >> 16));
  }
  for(int i=0;i<rem;i++){
    uint2 q = cp[i];
    float c = __uint_as_float(q.y);
    uint2 v = *(const uint2*)(T + (size_t)q.x*128 + c0);
    a0 += c*us2f((us16)(v.x & 0xffffu));
    a1 += c*us2f((us16)(v.x >> 16));
    a2 += c*us2f((us16)(v.y & 0xffffu));
    a3 += c*us2f((us16)(v.y >> 16));
  }
  float disr = dis[r]; float invdeg = disr*disr;
  uint2 vs = *(const uint2*)(T + (size_t)r*128 + c0);
  float4 bi = *(const float4*)(bias + c0);
  float4 ga = *(const float4*)(gamma + c0);
  float4 be = *(const float4*)(beta + c0);
  float4 rmv= *(const float4*)(rm + c0);
  float4 rvv= *(const float4*)(rv + c0);
  float o0 = a0*disr + us2f((us16)(vs.x & 0xffffu))*invdeg + bi.x;
  float o1 = a1*disr + us2f((us16)(vs.x >> 16))*invdeg + bi.y;
  float o2 = a2*disr + us2f((us16)(vs.y & 0xffffu))*invdeg + bi.z;
  float o3 = a3*disr + us2f((us16)(vs.y >> 16))*invdeg + bi.w;
  o0 = (o0 - rmv.x)*(ga.x*rsqrtf(rvv.x + 1e-5f)) + be.x;
  o1 = (o1 - rmv.y)*(ga.y*rsqrtf(rvv.y + 1e-5f)) + be.y;
  o2 = (o2 - rmv.z)*(ga.z*rsqrtf(rvv.z + 1e-5f)) + be.z;
  o3 = (o3 - rmv.w)*(ga.w*rsqrtf(rvv.w + 1e-5f)) + be.w;
  if (relu){
    o0=fmaxf(o0,0.f); o1=fmaxf(o1,0.f); o2=fmaxf(o2,0.f); o3=fmaxf(o3,0.f);
  }
  if (resid){
    uint2 vr = *(const uint2*)(resid + (size_t)r*128 + c0);
    o0 += us2f((us16)(vr.x & 0xffffu));
    o1 += us2f((us16)(vr.x >> 16));
    o2 += us2f((us16)(vr.y & 0xffffu));
    o3 += us2f((us16)(vr.y >> 16));
  }
  uint2 up;
  up.x = (unsigned)f2us(o0) | ((unsigned)f2us(o1) << 16);
  up.y = (unsigned)f2us(o2) | ((unsigned)f2us(o3) << 16);
  *(uint2*)(out + (size_t)r*128 + c0) = up;
}

// ---- FUSED: [agg-chain0 | agg-chain1] (doubles resident gather streams) ----
__global__ __launch_bounds__(256) void k_agg2(int AB,
  const uint2* __restrict__ csr, const int* __restrict__ rp, const int* __restrict__ cnt,
  const float* __restrict__ disA,
  const us16* __restrict__ Ta,
  const float* __restrict__ ba, const float* __restrict__ gaa, const float* __restrict__ bea,
  const float* __restrict__ rma, const float* __restrict__ rva,
  const us16* __restrict__ resida, us16* __restrict__ outa, int relua,
  const us16* __restrict__ Tb,
  const float* __restrict__ bb, const float* __restrict__ gab, const float* __restrict__ beb,
  const float* __restrict__ rmb, const float* __restrict__ rvb,
  const us16* __restrict__ residb, us16* __restrict__ outb, int relub, int n){
  int b = blockIdx.x;
  if (b < AB)
    agg_body(b, Ta, csr, rp, cnt, 0, disA, ba,gaa,bea,rma,rva, resida, outa, relua, n);
  else
    agg_body(b-AB, Tb, csr, rp, cnt, N_NODES, disA+N_NODES, bb,gab,beb,rmb,rvb, residb, outb, relub, n);
}

// ------------- seed constant -------------
__global__ void k_const64(const us16* __restrict__ X0, const us16* __restrict__ X1,
                          const int* __restrict__ seed,
                          const float* __restrict__ pw1, const float* __restrict__ pb1,
                          float* __restrict__ c64){
  int j = threadIdx.x;  // 64 threads
  int s = seed[0];
  const us16* x0 = X0 + (size_t)s*128;
  const us16* x1 = X1 + (size_t)s*128;
  float acc = pb1[j];
  #pragma unroll 8
  for(int k=0;k<128;k++) acc += us2f(x0[k]) * pw1[(256+k)*64 + j];
  #pragma unroll 8
  for(int k=0;k<128;k++) acc += us2f(x1[k]) * pw1[(384+k)*64 + j];
  c64[j]=acc;
}

// ------------- final dot -------------
__global__ __launch_bounds__(256) void k_outdot(const us16* __restrict__ Z2, const float* __restrict__ w3,
                                                const float* __restrict__ b3, float* __restrict__ out, int n){
  int r = blockIdx.x*256 + threadIdx.x;
  if(r>=n) return;
  const us16* z = Z2 + (size_t)r*64;
  float acc = b3[0];
  #pragma unroll 8
  for(int j=0;j<64;j++) acc += us2f(z[j])*w3[j];
  out[r]=acc;
}

extern "C" void kernel_launch(void* const* d_in, const int* in_sizes, int n_in,
                              void* d_out, int out_size, void* d_ws, size_t ws_size,
                              hipStream_t stream){
  const int N = N_NODES;
  const int E = in_sizes[2];
  const float* x   = (const float*)d_in[0];
  const int*   ei  = (const int*)d_in[1];
  const int*   et  = (const int*)d_in[2];
  const float* ew  = (const float*)d_in[3];
  const int*   seed= (const int*)d_in[4];
  const float* ft_w= (const float*)d_in[5];
  const float* ft_b= (const float*)d_in[6];
  const float* g0_w= (const float*)d_in[7];
  const float* g0_b= (const float*)d_in[8];
  const float* g0_g= (const float*)d_in[9];
  const float* g0_be=(const float*)d_in[10];
  const float* g0_rm=(const float*)d_in[11];
  const float* g0_rv=(const float*)d_in[12];
  const float* g1_w= (const float*)d_in[13];
  const float* g1_b= (const float*)d_in[14];
  const float* g1_g= (const float*)d_in[15];
  const float* g1_be=(const float*)d_in[16];
  const float* g1_rm=(const float*)d_in[17];
  const float* g1_rv=(const float*)d_in[18];
  const float* p_w1= (const float*)d_in[19];
  const float* p_b1= (const float*)d_in[20];
  const float* p_w2= (const float*)d_in[21];
  const float* p_b2= (const float*)d_in[22];
  const float* p_w3= (const float*)d_in[23];
  const float* p_b3= (const float*)d_in[24];
  float* out = (float*)d_out;

  // Footprint ~117.8 MB (< proven 119.2 MB). eofs aliases B3 (first written at agg1 -> h1).
  char* wsp = (char*)d_ws;
  auto alloc = [&](size_t bytes)->char*{ char* p = wsp; wsp += (bytes + 255) & ~(size_t)255; return p; };
  us16* B0 = (us16*)alloc((size_t)N*128*2);
  us16* B1 = (us16*)alloc((size_t)N*128*2);
  us16* B2 = (us16*)alloc((size_t)N*128*2);
  us16* B3 = (us16*)alloc((size_t)N*128*2);
  uint2* csr = (uint2*)alloc((size_t)E*8);
  float* disA=(float*)alloc((size_t)2*N*4);
  int* cnt =(int*)alloc((size_t)2*N*4);
  int* rp  =(int*)alloc((size_t)2*N*4);
  int* bsum=(int*)alloc(4096);
  float* c64=(float*)alloc(256);
  us16* wt =(us16*)alloc((size_t)102400*2);
  int* eofs = (int*)B3;
  us16* Z1 = B1;                 // free after x0/x1 land in B0/B3
  us16* Z2 = B1 + (size_t)N*64;

  const int* srcp = ei;
  const int* dstp = ei + E;

  int M = 2*N;
  int CB = (E+255)/256;
  int GB = (N+127)/128;
  int AB = (N+7)/8;
  int SB = (M+2047)/2048;
  int DB = (M+255)/256;

  // ---- prep ----
  k_init<<<(M+255)/256,256,0,stream>>>(cnt,M);
  dim3 pg(64,7);
  k_prepw<<<pg,256,0,stream>>>(ft_w,g0_w,g1_w,p_w1,p_w2,wt);

  const us16* wt_ft = wt;
  const us16* wt_g00= wt+16384;
  const us16* wt_g01= wt+32768;
  const us16* wt_g10= wt+49152;
  const us16* wt_g11= wt+65536;
  const us16* wt_p1 = wt+81920;
  const us16* wt_p2 = wt+98304;

  // ---- graph build + feature transform ----
  k_cnt<<<CB,256,0,stream>>>(dstp,et,cnt,eofs,E);
  k_scan_reduce<<<SB,256,0,stream>>>(cnt,bsum,M);
  k_scan_top<<<1,64,0,stream>>>(bsum,SB);
  k_scan_apply<<<SB,256,0,stream>>>(cnt,bsum,rp,M);
  k_fill_ft<<<CB+GB,256,0,stream>>>(srcp,dstp,et,ew,rp,eofs,csr,E,CB, x,wt_ft,ft_b,B0,N);
  k_deg_l0<<<DB+2*GB,256,0,stream>>>(csr,rp,cnt,disA,M,DB,GB, B0,wt_g00,wt_g10,B1,B2,N);
  k_coef<<<(E+255)/256,256,0,stream>>>(csr,rp,disA,E);

  // ---- parallel chains ----
  // stage 1: [agg0: B1 -> B0 (h0) | agg1: B2 -> B3 (h1)]
  k_agg2<<<2*AB,256,0,stream>>>(AB, csr,rp,cnt,disA,
      B1, g0_b,g0_g,g0_be,g0_rm,g0_rv, nullptr, B0, 1,
      B2, g1_b,g1_g,g1_be,g1_rm,g1_rv, nullptr, B3, 1, N);
  // stage 2: [g01: B0 -> B1 | g11: B3 -> B2]
  k_gemm2<<<2*GB,256,0,stream>>>(GB, B0,wt_g01,B1, B3,wt_g11,B2, N);
  // stage 3: [agg0b: B1 + resid B0 -> B0 (x0, in-place) | agg1b: B2 + resid B3 -> B3 (x1, in-place)]
  k_agg2<<<2*AB,256,0,stream>>>(AB, csr,rp,cnt,disA,
      B1, g0_b+128,g0_g+128,g0_be+128,g0_rm+128,g0_rv+128, B0, B0, 0,
      B2, g1_b+128,g1_g+128,g1_be+128,g1_rm+128,g1_rv+128, B3, B3, 0, N);

  // ---- predictor: x0=B0, x1=B3 ----
  k_const64<<<1,64,0,stream>>>(B0,B3,seed,p_w1,p_b1,c64);
  k_mgemm<64,us16><<<GB,256,0,stream>>>(B0,B3,128, wt_p1, nullptr, c64, Z1,64, N,256,1);
  k_mgemm<64,us16><<<GB,256,0,stream>>>(Z1,Z1,64,  wt_p2, p_b2, nullptr, Z2,64, N,64,1);
  k_outdot<<<(N+255)/256,256,0,stream>>>(Z2,p_w3,p_b3,out,N);
}

// Round 15
// 397.480 us; speedup vs baseline: 1.3464x; 1.0395x over previous
//
#include <hip/hip_runtime.h>
#include <hip/hip_bf16.h>
#include <stdint.h>

#define N_NODES 100000

typedef unsigned short us16;
typedef short bf16x8 __attribute__((ext_vector_type(8)));
typedef float f32x4 __attribute__((ext_vector_type(4)));

__device__ __forceinline__ float us2f(us16 u){
  union{ unsigned int i; float f; } x; x.i = ((unsigned int)u) << 16; return x.f;
}
__device__ __forceinline__ us16 f2us(float f){
  union{ float f; unsigned int i; } x; x.f = f;
  unsigned int i = x.i;
  unsigned int r = (i + 0x7FFFu + ((i >> 16) & 1u)) >> 16;
  return (us16)r;
}

// ---------------- init: zero cnt ----------------
__global__ __launch_bounds__(256) void k_init(int* __restrict__ cnt, int n2){
  int i = blockIdx.x*256 + threadIdx.x;
  if (i < n2) cnt[i]=0;
}

// ------- per-(type,dst) counts: standalone (atomics need full occupancy — R13 lesson) -------
__global__ __launch_bounds__(256) void k_cnt(const int* __restrict__ dst,
                                             const int* __restrict__ et,
                                             int* __restrict__ cnt,
                                             int* __restrict__ eofs, int E){
  int e = blockIdx.x*256 + threadIdx.x;
  if (e>=E) return;
  int d = dst[e]; int t = et[e];
  eofs[e] = atomicAdd(&cnt[t*N_NODES + d], 1);
}

// ---------------- exclusive scan over M elements (R1-exact) ----------------
__global__ __launch_bounds__(256) void k_scan_reduce(const int* __restrict__ in, int* __restrict__ bsum, int M){
  __shared__ int sd[256];
  int base = blockIdx.x*2048; int t = threadIdx.x;
  int sum = 0;
  #pragma unroll
  for(int i=0;i<8;i++){ int p = base + t*8 + i; if(p<M) sum += in[p]; }
  sd[t]=sum; __syncthreads();
  for(int s=128;s>0;s>>=1){ if(t<s) sd[t]+=sd[t+s]; __syncthreads(); }
  if(t==0) bsum[blockIdx.x]=sd[0];
}
__global__ void k_scan_top(int* __restrict__ bsum, int B){
  if (threadIdx.x==0){ int run=0; for(int i=0;i<B;i++){ int v=bsum[i]; bsum[i]=run; run+=v; } }
}
__global__ __launch_bounds__(256) void k_scan_apply(const int* __restrict__ in, const int* __restrict__ bsum,
                                                    int* __restrict__ out, int M){
  __shared__ int sd[256];
  int base = blockIdx.x*2048; int t = threadIdx.x;
  int loc[8]; int sum=0;
  #pragma unroll
  for(int i=0;i<8;i++){ int p = base + t*8 + i; int v = (p<M)?in[p]:0; loc[i]=sum; sum+=v; }
  sd[t]=sum; __syncthreads();
  for(int ofs=1;ofs<256;ofs<<=1){
    int v = (t>=ofs)? sd[t-ofs] : 0;
    __syncthreads();
    sd[t]+=v;
    __syncthreads();
  }
  int excl = ((t==0)?0:sd[t-1]) + bsum[blockIdx.x];
  #pragma unroll
  for(int i=0;i<8;i++){ int p = base + t*8 + i; if(p<M) out[p]=excl+loc[i]; }
}

// ---------------- fold dis[src] into coefficients (R8-proven): coef = w * dis[s] ----------------
__global__ __launch_bounds__(256) void k_coef(uint2* __restrict__ csr,
                                              const int* __restrict__ rp,
                                              const float* __restrict__ disA, int E){
  int e = blockIdx.x*256+threadIdx.x;
  if(e>=E) return;
  int rpN = rp[N_NODES];               // boundary: first type-1 entry
  int t = (e >= rpN) ? 1 : 0;
  uint2 q = csr[e];
  float w = __uint_as_float(q.y) * disA[t*N_NODES + (int)q.x];
  csr[e] = make_uint2(q.x, __float_as_uint(w));
}

// ---------------- weight prep: f32 [K][NC] -> bf16 transposed [NC][K] ----------------
__global__ __launch_bounds__(256) void k_prepw(const float* __restrict__ ft_w,
                                               const float* __restrict__ g0_w, const float* __restrict__ g1_w,
                                               const float* __restrict__ p_w1, const float* __restrict__ p_w2,
                                               us16* __restrict__ wt){
  int m = blockIdx.y;
  const float* srcp; int K, NCc; us16* dstp;
  switch(m){
    case 0: srcp=ft_w;        K=128; NCc=128; dstp=wt;        break;
    case 1: srcp=g0_w;        K=128; NCc=128; dstp=wt+16384;  break;
    case 2: srcp=g0_w+16384;  K=128; NCc=128; dstp=wt+32768;  break;
    case 3: srcp=g1_w;        K=128; NCc=128; dstp=wt+49152;  break;
    case 4: srcp=g1_w+16384;  K=128; NCc=128; dstp=wt+65536;  break;
    case 5: srcp=p_w1;        K=256; NCc=64;  dstp=wt+81920;  break;
    default:srcp=p_w2;        K=64;  NCc=64;  dstp=wt+98304;  break;
  }
  int idx = blockIdx.x*256+threadIdx.x;
  if(idx >= K*NCc) return;
  int nn = idx / K, k = idx - nn*K;
  dstp[idx] = f2us(srcp[(size_t)k*NCc + nn]);
}

// ---------- MFMA GEMM body (R6-verified core): C[n,NC](bf16) = A@W (+bias/addv, relu) ----------
template<int NC, typename AT>
__device__ __forceinline__ void mgemm_body(int bid,
                 const AT* __restrict__ A0, const AT* __restrict__ A1,
                 int lda, const us16* __restrict__ Wt,
                 const float* __restrict__ bias, const float* __restrict__ addv,
                 us16* __restrict__ C, int ldc, int n, int KC, int relu,
                 us16* Alds, us16* Wlds){
  constexpr int NB = NC/16;
  const int tid = threadIdx.x;
  const int lane = tid & 63, wid = tid >> 6;
  const int rowBase = bid*128;
  f32x4 zero = {0.f,0.f,0.f,0.f};
  f32x4 acc[2][NB];
  #pragma unroll
  for(int m=0;m<2;m++)
    #pragma unroll
    for(int nb=0;nb<NB;nb++) acc[m][nb] = zero;

  for(int kk=0; kk<KC; kk+=64){
    const AT* Ab = (kk<128)? A0 : A1;
    const int kc = (kk<128)? kk : (kk-128);
    #pragma unroll
    for(int p=0;p<4;p++){
      int idx = p*256 + tid;
      int r = idx>>3, u = idx&7;
      int row = rowBase + r;
      uint4 v = make_uint4(0u,0u,0u,0u);
      if(row<n){
        if constexpr (sizeof(AT)==2){
          v = *(const uint4*)(Ab + (size_t)row*lda + kc + u*8);
        } else {
          float4 f0 = *(const float4*)(Ab + (size_t)row*lda + kc + u*8);
          float4 f1 = *(const float4*)(Ab + (size_t)row*lda + kc + u*8 + 4);
          us16 tmp[8] = {f2us(f0.x),f2us(f0.y),f2us(f0.z),f2us(f0.w),
                         f2us(f1.x),f2us(f1.y),f2us(f1.z),f2us(f1.w)};
          v = *(const uint4*)tmp;
        }
      }
      *(uint4*)&Alds[(r*8 + (u ^ (r&7)))*8] = v;
    }
    #pragma unroll
    for(int p=0;p<NB/2;p++){
      int idx = p*256 + tid;
      int cI = idx>>3, u = idx&7;
      uint4 v = *(const uint4*)(Wt + (size_t)cI*KC + kk + u*8);
      *(uint4*)&Wlds[(cI*8 + (u ^ (cI&7)))*8] = v;
    }
    __syncthreads();
    #pragma unroll
    for(int ks=0;ks<2;ks++){
      bf16x8 af[2];
      #pragma unroll
      for(int m=0;m<2;m++){
        int r = wid*32 + m*16 + (lane&15);
        int u = (ks*4 + (lane>>4)) ^ (r&7);
        af[m] = *(const bf16x8*)&Alds[(r*8+u)*8];
      }
      #pragma unroll
      for(int nb=0;nb<NB;nb++){
        int c2 = nb*16 + (lane&15);
        int u = (ks*4 + (lane>>4)) ^ (c2&7);
        bf16x8 bfv = *(const bf16x8*)&Wlds[(c2*8+u)*8];
        #pragma unroll
        for(int m=0;m<2;m++)
          acc[m][nb] = __builtin_amdgcn_mfma_f32_16x16x32_bf16(af[m], bfv, acc[m][nb], 0,0,0);
      }
    }
    __syncthreads();
  }
  #pragma unroll
  for(int nb=0;nb<NB;nb++){
    int col = nb*16 + (lane&15);
    float badd = (bias? bias[col]:0.f) + (addv? addv[col]:0.f);
    #pragma unroll
    for(int m=0;m<2;m++){
      #pragma unroll
      for(int j=0;j<4;j++){
        int row = rowBase + wid*32 + m*16 + (lane>>4)*4 + j;
        if(row<n){
          float v = acc[m][nb][j] + badd;
          if(relu) v = fmaxf(v,0.f);
          C[(size_t)row*ldc + col] = f2us(v);
        }
      }
    }
  }
}

// standalone GEMM kernel (predictor)
template<int NC, typename AT>
__global__ __launch_bounds__(256) void k_mgemm(const AT* __restrict__ A0, const AT* __restrict__ A1,
                 int lda, const us16* __restrict__ Wt,
                 const float* __restrict__ bias, const float* __restrict__ addv,
                 us16* __restrict__ C, int ldc, int n, int KC, int relu){
  __shared__ us16 smem[128*64 + NC*64];
  mgemm_body<NC,AT>(blockIdx.x, A0,A1,lda, Wt, bias,addv, C,ldc, n,KC,relu, smem, smem+128*64);
}

// ---- FUSED: [fill | ft-GEMM] (scatter-store tolerates reduced occupancy — R13 lesson) ----
__global__ __launch_bounds__(256) void k_fill_ft(
    const int* __restrict__ src, const int* __restrict__ dst,
    const int* __restrict__ et, const float* __restrict__ ew,
    const int* __restrict__ rp, const int* __restrict__ eofs,
    uint2* __restrict__ csr, int E, int CB,
    const float* __restrict__ x, const us16* __restrict__ wt_ft, const float* __restrict__ ft_b,
    us16* __restrict__ B0, int n){
  __shared__ us16 smem[128*64 + 128*64];
  int b = blockIdx.x;
  if (b < CB){
    int e = b*256 + threadIdx.x;
    if (e < E){
      int s=src[e], d=dst[e], t=et[e]; float w=ew[e];
      int idx = t*N_NODES + d;
      int pos = rp[idx] + eofs[e];
      csr[pos] = make_uint2((unsigned)s, __float_as_uint(w));
    }
  } else {
    mgemm_body<128,float>(b - CB, x, x, 128, wt_ft, ft_b, nullptr, B0, 128, n, 128, 1,
                          smem, smem + 128*64);
  }
}

// ---- FUSED: [deg | g00 | g10] ----
__global__ __launch_bounds__(256) void k_deg_l0(
    const uint2* __restrict__ csr, const int* __restrict__ rp, const int* __restrict__ cnt,
    float* __restrict__ disA, int M, int DB, int GB,
    const us16* __restrict__ B0,
    const us16* __restrict__ wt_g00, const us16* __restrict__ wt_g10,
    us16* __restrict__ B1, us16* __restrict__ B2, int n){
  __shared__ us16 smem[128*64 + 128*64];
  int b = blockIdx.x;
  if (b < DB){
    int i = b*256 + threadIdx.x;
    if (i < M){
      int e0 = rp[i], c = cnt[i];
      float s = 1.0f;
      for(int e=e0; e<e0+c; e++) s += __uint_as_float(csr[e].y);
      disA[i] = rsqrtf(s);
    }
  } else if (b < DB + GB){
    mgemm_body<128,us16>(b - DB, B0, B0, 128, wt_g00, nullptr, nullptr, B1, 128, n, 128, 0,
                         smem, smem + 128*64);
  } else {
    mgemm_body<128,us16>(b - DB - GB, B0, B0, 128, wt_g10, nullptr, nullptr, B2, 128, n, 128, 0,
                         smem, smem + 128*64);
  }
}

// ---- FUSED: [gemmA | gemmB] (both 128-col, bf16 A) ----
__global__ __launch_bounds__(256) void k_gemm2(int GB,
    const us16* __restrict__ Aa, const us16* __restrict__ Wa, us16* __restrict__ Ca,
    const us16* __restrict__ Ab, const us16* __restrict__ Wb, us16* __restrict__ Cb, int n){
  __shared__ us16 smem[128*64 + 128*64];
  int b = blockIdx.x;
  if (b < GB)
    mgemm_body<128,us16>(b, Aa, Aa, 128, Wa, nullptr, nullptr, Ca, 128, n, 128, 0, smem, smem+128*64);
  else
    mgemm_body<128,us16>(b-GB, Ab, Ab, 128, Wb, nullptr, nullptr, Cb, 128, n, 128, 0, smem, smem+128*64);
}

// --- aggregation body: 4 rows/wave (quarter-wave per row), 16 lanes x uint4 slices, chunk-4 ---
// Halves load instructions per edge vs 8B slices; 4 independent row streams per wave.
__device__ __forceinline__ void agg_body(int bid, const us16* __restrict__ T,
  const uint2* __restrict__ csr,
  const int* __restrict__ rp, const int* __restrict__ cnt, int rowOfs,
  const float* __restrict__ dis,
  const float* __restrict__ bias, const float* __restrict__ gamma, const float* __restrict__ beta,
  const float* __restrict__ rm, const float* __restrict__ rv,
  const us16* __restrict__ resid,
  us16* __restrict__ out, int relu, int n){
  const int wid = threadIdx.x >> 6, lane = threadIdx.x & 63;
  const int qg = lane >> 4;        // quarter-wave: row within wave
  const int sl = lane & 15;        // 16B slot in row (8 bf16 cols)
  int r = bid*16 + wid*4 + qg;
  if (r >= n) return;
  const int c0 = sl*8;
  int idx = rowOfs + r;
  int e0 = rp[idx];
  int ec = cnt[idx];
  const uint2* cp = csr + e0;
  float a[8];
  #pragma unroll
  for(int j=0;j<8;j++) a[j]=0.f;
  int nchunk = ec >> 2;
  int rem = ec & 3;
  for(int ch=0; ch<nchunk; ch++){
    uint2 q[4];
    #pragma unroll
    for(int i=0;i<4;i++) q[i] = cp[i];
    cp += 4;
    uint4 v[4];
    #pragma unroll
    for(int i=0;i<4;i++) v[i] = *(const uint4*)(T + (size_t)q[i].x*128 + c0);
    #pragma unroll
    for(int i=0;i<4;i++){
      float c = __uint_as_float(q[i].y);
      a[0] += c*us2f((us16)(v[i].x & 0xffffu));
      a[1] += c*us2f((us16)(v[i].x >> 16));
      a[2] += c*us2f((us16)(v[i].y & 0xffffu));
      a[3] += c*us2f((us16)(v[i].y >> 16));
      a[4] += c*us2f((us16)(v[i].z & 0xffffu));
      a[5] += c*us2f((us16)(v[i].z >> 16));
      a[6] += c*us2f((us16)(v[i].w & 0xffffu));
      a[7] += c*us2f((us16)(v[i].w >> 16));
    }
  }
  for(int i=0;i<rem;i++){
    uint2 q = cp[i];
    float c = __uint_as_float(q.y);
    uint4 v = *(const uint4*)(T + (size_t)q.x*128 + c0);
    a[0] += c*us2f((us16)(v.x & 0xffffu));
    a[1] += c*us2f((us16)(v.x >> 16));
    a[2] += c*us2f((us16)(v.y & 0xffffu));
    a[3] += c*us2f((us16)(v.y >> 16));
    a[4] += c*us2f((us16)(v.z & 0xffffu));
    a[5] += c*us2f((us16)(v.z >> 16));
    a[6] += c*us2f((us16)(v.w & 0xffffu));
    a[7] += c*us2f((us16)(v.w >> 16));
  }
  float disr = dis[r]; float invdeg = disr*disr;
  uint4 vs = *(const uint4*)(T + (size_t)r*128 + c0);
  float s[8] = {
    us2f((us16)(vs.x & 0xffffu)), us2f((us16)(vs.x >> 16)),
    us2f((us16)(vs.y & 0xffffu)), us2f((us16)(vs.y >> 16)),
    us2f((us16)(vs.z & 0xffffu)), us2f((us16)(vs.z >> 16)),
    us2f((us16)(vs.w & 0xffffu)), us2f((us16)(vs.w >> 16))
  };
  float4 bi0 = *(const float4*)(bias + c0);
  float4 bi1 = *(const float4*)(bias + c0 + 4);
  float4 ga0 = *(const float4*)(gamma + c0);
  float4 ga1 = *(const float4*)(gamma + c0 + 4);
  float4 be0 = *(const float4*)(beta + c0);
  float4 be1 = *(const float4*)(beta + c0 + 4);
  float4 rm0 = *(const float4*)(rm + c0);
  float4 rm1 = *(const float4*)(rm + c0 + 4);
  float4 rv0 = *(const float4*)(rv + c0);
  float4 rv1 = *(const float4*)(rv + c0 + 4);
  float bif[8] = {bi0.x,bi0.y,bi0.z,bi0.w,bi1.x,bi1.y,bi1.z,bi1.w};
  float gaf[8] = {ga0.x,ga0.y,ga0.z,ga0.w,ga1.x,ga1.y,ga1.z,ga1.w};
  float bef[8] = {be0.x,be0.y,be0.z,be0.w,be1.x,be1.y,be1.z,be1.w};
  float rmf[8] = {rm0.x,rm0.y,rm0.z,rm0.w,rm1.x,rm1.y,rm1.z,rm1.w};
  float rvf[8] = {rv0.x,rv0.y,rv0.z,rv0.w,rv1.x,rv1.y,rv1.z,rv1.w};
  float o[8];
  #pragma unroll
  for(int j=0;j<8;j++){
    float v = a[j]*disr + s[j]*invdeg + bif[j];
    v = (v - rmf[j])*(gaf[j]*rsqrtf(rvf[j] + 1e-5f)) + bef[j];
    if (relu) v = fmaxf(v,0.f);
    o[j] = v;
  }
  if (resid){
    uint4 vr = *(const uint4*)(resid + (size_t)r*128 + c0);
    o[0] += us2f((us16)(vr.x & 0xffffu));
    o[1] += us2f((us16)(vr.x >> 16));
    o[2] += us2f((us16)(vr.y & 0xffffu));
    o[3] += us2f((us16)(vr.y >> 16));
    o[4] += us2f((us16)(vr.z & 0xffffu));
    o[5] += us2f((us16)(vr.z >> 16));
    o[6] += us2f((us16)(vr.w & 0xffffu));
    o[7] += us2f((us16)(vr.w >> 16));
  }
  uint4 up;
  up.x = (unsigned)f2us(o[0]) | ((unsigned)f2us(o[1]) << 16);
  up.y = (unsigned)f2us(o[2]) | ((unsigned)f2us(o[3]) << 16);
  up.z = (unsigned)f2us(o[4]) | ((unsigned)f2us(o[5]) << 16);
  up.w = (unsigned)f2us(o[6]) | ((unsigned)f2us(o[7]) << 16);
  *(uint4*)(out + (size_t)r*128 + c0) = up;
}

// ---- FUSED: [agg-chain0 | agg-chain1] (doubles resident gather streams) ----
__global__ __launch_bounds__(256) void k_agg2(int AB,
  const uint2* __restrict__ csr, const int* __restrict__ rp, const int* __restrict__ cnt,
  const float* __restrict__ disA,
  const us16* __restrict__ Ta,
  const float* __restrict__ ba, const float* __restrict__ gaa, const float* __restrict__ bea,
  const float* __restrict__ rma, const float* __restrict__ rva,
  const us16* __restrict__ resida, us16* __restrict__ outa, int relua,
  const us16* __restrict__ Tb,
  const float* __restrict__ bb, const float* __restrict__ gab, const float* __restrict__ beb,
  const float* __restrict__ rmb, const float* __restrict__ rvb,
  const us16* __restrict__ residb, us16* __restrict__ outb, int relub, int n){
  int b = blockIdx.x;
  if (b < AB)
    agg_body(b, Ta, csr, rp, cnt, 0, disA, ba,gaa,bea,rma,rva, resida, outa, relua, n);
  else
    agg_body(b-AB, Tb, csr, rp, cnt, N_NODES, disA+N_NODES, bb,gab,beb,rmb,rvb, residb, outb, relub, n);
}

// ------------- seed constant -------------
__global__ void k_const64(const us16* __restrict__ X0, const us16* __restrict__ X1,
                          const int* __restrict__ seed,
                          const float* __restrict__ pw1, const float* __restrict__ pb1,
                          float* __restrict__ c64){
  int j = threadIdx.x;  // 64 threads
  int s = seed[0];
  const us16* x0 = X0 + (size_t)s*128;
  const us16* x1 = X1 + (size_t)s*128;
  float acc = pb1[j];
  #pragma unroll 8
  for(int k=0;k<128;k++) acc += us2f(x0[k]) * pw1[(256+k)*64 + j];
  #pragma unroll 8
  for(int k=0;k<128;k++) acc += us2f(x1[k]) * pw1[(384+k)*64 + j];
  c64[j]=acc;
}

// ------------- final dot -------------
__global__ __launch_bounds__(256) void k_outdot(const us16* __restrict__ Z2, const float* __restrict__ w3,
                                                const float* __restrict__ b3, float* __restrict__ out, int n){
  int r = blockIdx.x*256 + threadIdx.x;
  if(r>=n) return;
  const us16* z = Z2 + (size_t)r*64;
  float acc = b3[0];
  #pragma unroll 8
  for(int j=0;j<64;j++) acc += us2f(z[j])*w3[j];
  out[r]=acc;
}

extern "C" void kernel_launch(void* const* d_in, const int* in_sizes, int n_in,
                              void* d_out, int out_size, void* d_ws, size_t ws_size,
                              hipStream_t stream){
  const int N = N_NODES;
  const int E = in_sizes[2];
  const float* x   = (const float*)d_in[0];
  const int*   ei  = (const int*)d_in[1];
  const int*   et  = (const int*)d_in[2];
  const float* ew  = (const float*)d_in[3];
  const int*   seed= (const int*)d_in[4];
  const float* ft_w= (const float*)d_in[5];
  const float* ft_b= (const float*)d_in[6];
  const float* g0_w= (const float*)d_in[7];
  const float* g0_b= (const float*)d_in[8];
  const float* g0_g= (const float*)d_in[9];
  const float* g0_be=(const float*)d_in[10];
  const float* g0_rm=(const float*)d_in[11];
  const float* g0_rv=(const float*)d_in[12];
  const float* g1_w= (const float*)d_in[13];
  const float* g1_b= (const float*)d_in[14];
  const float* g1_g= (const float*)d_in[15];
  const float* g1_be=(const float*)d_in[16];
  const float* g1_rm=(const float*)d_in[17];
  const float* g1_rv=(const float*)d_in[18];
  const float* p_w1= (const float*)d_in[19];
  const float* p_b1= (const float*)d_in[20];
  const float* p_w2= (const float*)d_in[21];
  const float* p_b2= (const float*)d_in[22];
  const float* p_w3= (const float*)d_in[23];
  const float* p_b3= (const float*)d_in[24];
  float* out = (float*)d_out;

  // Footprint ~117.8 MB (< proven 119.2 MB). eofs aliases B3 (first written at agg1 -> h1).
  char* wsp = (char*)d_ws;
  auto alloc = [&](size_t bytes)->char*{ char* p = wsp; wsp += (bytes + 255) & ~(size_t)255; return p; };
  us16* B0 = (us16*)alloc((size_t)N*128*2);
  us16* B1 = (us16*)alloc((size_t)N*128*2);
  us16* B2 = (us16*)alloc((size_t)N*128*2);
  us16* B3 = (us16*)alloc((size_t)N*128*2);
  uint2* csr = (uint2*)alloc((size_t)E*8);
  float* disA=(float*)alloc((size_t)2*N*4);
  int* cnt =(int*)alloc((size_t)2*N*4);
  int* rp  =(int*)alloc((size_t)2*N*4);
  int* bsum=(int*)alloc(4096);
  float* c64=(float*)alloc(256);
  us16* wt =(us16*)alloc((size_t)102400*2);
  int* eofs = (int*)B3;
  us16* Z1 = B1;                 // free after x0/x1 land in B0/B3
  us16* Z2 = B1 + (size_t)N*64;

  const int* srcp = ei;
  const int* dstp = ei + E;

  int M = 2*N;
  int CB = (E+255)/256;
  int GB = (N+127)/128;
  int AB = (N+15)/16;
  int SB = (M+2047)/2048;
  int DB = (M+255)/256;

  // ---- prep ----
  k_init<<<(M+255)/256,256,0,stream>>>(cnt,M);
  dim3 pg(64,7);
  k_prepw<<<pg,256,0,stream>>>(ft_w,g0_w,g1_w,p_w1,p_w2,wt);

  const us16* wt_ft = wt;
  const us16* wt_g00= wt+16384;
  const us16* wt_g01= wt+32768;
  const us16* wt_g10= wt+49152;
  const us16* wt_g11= wt+65536;
  const us16* wt_p1 = wt+81920;
  const us16* wt_p2 = wt+98304;

  // ---- graph build + feature transform ----
  k_cnt<<<CB,256,0,stream>>>(dstp,et,cnt,eofs,E);
  k_scan_reduce<<<SB,256,0,stream>>>(cnt,bsum,M);
  k_scan_top<<<1,64,0,stream>>>(bsum,SB);
  k_scan_apply<<<SB,256,0,stream>>>(cnt,bsum,rp,M);
  k_fill_ft<<<CB+GB,256,0,stream>>>(srcp,dstp,et,ew,rp,eofs,csr,E,CB, x,wt_ft,ft_b,B0,N);
  k_deg_l0<<<DB+2*GB,256,0,stream>>>(csr,rp,cnt,disA,M,DB,GB, B0,wt_g00,wt_g10,B1,B2,N);
  k_coef<<<(E+255)/256,256,0,stream>>>(csr,rp,disA,E);

  // ---- parallel chains ----
  // stage 1: [agg0: B1 -> B0 (h0) | agg1: B2 -> B3 (h1)]
  k_agg2<<<2*AB,256,0,stream>>>(AB, csr,rp,cnt,disA,
      B1, g0_b,g0_g,g0_be,g0_rm,g0_rv, nullptr, B0, 1,
      B2, g1_b,g1_g,g1_be,g1_rm,g1_rv, nullptr, B3, 1, N);
  // stage 2: [g01: B0 -> B1 | g11: B3 -> B2]
  k_gemm2<<<2*GB,256,0,stream>>>(GB, B0,wt_g01,B1, B3,wt_g11,B2, N);
  // stage 3: [agg0b: B1 + resid B0 -> B0 (x0, in-place) | agg1b: B2 + resid B3 -> B3 (x1, in-place)]
  k_agg2<<<2*AB,256,0,stream>>>(AB, csr,rp,cnt,disA,
      B1, g0_b+128,g0_g+128,g0_be+128,g0_rm+128,g0_rv+128, B0, B0, 0,
      B2, g1_b+128,g1_g+128,g1_be+128,g1_rm+128,g1_rv+128, B3, B3, 0, N);

  // ---- predictor: x0=B0, x1=B3 ----
  k_const64<<<1,64,0,stream>>>(B0,B3,seed,p_w1,p_b1,c64);
  k_mgemm<64,us16><<<GB,256,0,stream>>>(B0,B3,128, wt_p1, nullptr, c64, Z1,64, N,256,1);
  k_mgemm<64,us16><<<GB,256,0,stream>>>(Z1,Z1,64,  wt_p2, p_b2, nullptr, Z2,64, N,64,1);
  k_outdot<<<(N+255)/256,256,0,stream>>>(Z2,p_w3,p_b3,out,N);
}

// Round 16
// 391.964 us; speedup vs baseline: 1.3654x; 1.0141x over previous
//
#include <hip/hip_runtime.h>
#include <hip/hip_bf16.h>
#include <stdint.h>

#define N_NODES 100000

typedef unsigned short us16;
typedef short bf16x8 __attribute__((ext_vector_type(8)));
typedef float f32x4 __attribute__((ext_vector_type(4)));

__device__ __forceinline__ float us2f(us16 u){
  union{ unsigned int i; float f; } x; x.i = ((unsigned int)u) << 16; return x.f;
}
__device__ __forceinline__ us16 f2us(float f){
  union{ float f; unsigned int i; } x; x.f = f;
  unsigned int i = x.i;
  unsigned int r = (i + 0x7FFFu + ((i >> 16) & 1u)) >> 16;
  return (us16)r;
}

// ---------------- init: zero cnt ----------------
__global__ __launch_bounds__(256) void k_init(int* __restrict__ cnt, int n2){
  int i = blockIdx.x*256 + threadIdx.x;
  if (i < n2) cnt[i]=0;
}

// ------- per-(type,dst) counts: standalone (atomics need full occupancy — R13 lesson) -------
__global__ __launch_bounds__(256) void k_cnt(const int* __restrict__ dst,
                                             const int* __restrict__ et,
                                             int* __restrict__ cnt,
                                             int* __restrict__ eofs, int E){
  int e = blockIdx.x*256 + threadIdx.x;
  if (e>=E) return;
  int d = dst[e]; int t = et[e];
  eofs[e] = atomicAdd(&cnt[t*N_NODES + d], 1);
}

// ---------------- exclusive scan over M elements (R1-exact) ----------------
__global__ __launch_bounds__(256) void k_scan_reduce(const int* __restrict__ in, int* __restrict__ bsum, int M){
  __shared__ int sd[256];
  int base = blockIdx.x*2048; int t = threadIdx.x;
  int sum = 0;
  #pragma unroll
  for(int i=0;i<8;i++){ int p = base + t*8 + i; if(p<M) sum += in[p]; }
  sd[t]=sum; __syncthreads();
  for(int s=128;s>0;s>>=1){ if(t<s) sd[t]+=sd[t+s]; __syncthreads(); }
  if(t==0) bsum[blockIdx.x]=sd[0];
}
__global__ void k_scan_top(int* __restrict__ bsum, int B){
  if (threadIdx.x==0){ int run=0; for(int i=0;i<B;i++){ int v=bsum[i]; bsum[i]=run; run+=v; } }
}
__global__ __launch_bounds__(256) void k_scan_apply(const int* __restrict__ in, const int* __restrict__ bsum,
                                                    int* __restrict__ out, int M){
  __shared__ int sd[256];
  int base = blockIdx.x*2048; int t = threadIdx.x;
  int loc[8]; int sum=0;
  #pragma unroll
  for(int i=0;i<8;i++){ int p = base + t*8 + i; int v = (p<M)?in[p]:0; loc[i]=sum; sum+=v; }
  sd[t]=sum; __syncthreads();
  for(int ofs=1;ofs<256;ofs<<=1){
    int v = (t>=ofs)? sd[t-ofs] : 0;
    __syncthreads();
    sd[t]+=v;
    __syncthreads();
  }
  int excl = ((t==0)?0:sd[t-1]) + bsum[blockIdx.x];
  #pragma unroll
  for(int i=0;i<8;i++){ int p = base + t*8 + i; if(p<M) out[p]=excl+loc[i]; }
}

// ---------------- CSR fill: standalone, NO atomic (pos = rp + precomputed rank) ----------------
__global__ __launch_bounds__(256) void k_edge_fill(const int* __restrict__ src, const int* __restrict__ dst,
  const int* __restrict__ et, const float* __restrict__ ew,
  const int* __restrict__ rp, const int* __restrict__ eofs,
  uint2* __restrict__ csr, int E){
  int e = blockIdx.x*256+threadIdx.x;
  if(e>=E) return;
  int s=src[e], d=dst[e], t=et[e]; float w=ew[e];
  int idx = t*N_NODES + d;
  int pos = rp[idx] + eofs[e];
  csr[pos] = make_uint2((unsigned)s, __float_as_uint(w));
}

// ---------------- degree from CSR (standalone, atomic-free) ----------------
__global__ __launch_bounds__(256) void k_deg_csr(const uint2* __restrict__ csr,
                                                 const int* __restrict__ rp, const int* __restrict__ cnt,
                                                 float* __restrict__ disA, int M){
  int i = blockIdx.x*256+threadIdx.x;
  if(i>=M) return;
  int e0 = rp[i], c = cnt[i];
  float s = 1.0f;
  for(int e=e0; e<e0+c; e++) s += __uint_as_float(csr[e].y);
  disA[i] = rsqrtf(s);
}

// ---------------- weight prep: f32 [K][NC] -> bf16 transposed [NC][K] ----------------
__global__ __launch_bounds__(256) void k_prepw(const float* __restrict__ ft_w,
                                               const float* __restrict__ g0_w, const float* __restrict__ g1_w,
                                               const float* __restrict__ p_w1, const float* __restrict__ p_w2,
                                               us16* __restrict__ wt){
  int m = blockIdx.y;
  const float* srcp; int K, NCc; us16* dstp;
  switch(m){
    case 0: srcp=ft_w;        K=128; NCc=128; dstp=wt;        break;
    case 1: srcp=g0_w;        K=128; NCc=128; dstp=wt+16384;  break;
    case 2: srcp=g0_w+16384;  K=128; NCc=128; dstp=wt+32768;  break;
    case 3: srcp=g1_w;        K=128; NCc=128; dstp=wt+49152;  break;
    case 4: srcp=g1_w+16384;  K=128; NCc=128; dstp=wt+65536;  break;
    case 5: srcp=p_w1;        K=256; NCc=64;  dstp=wt+81920;  break;
    default:srcp=p_w2;        K=64;  NCc=64;  dstp=wt+98304;  break;
  }
  int idx = blockIdx.x*256+threadIdx.x;
  if(idx >= K*NCc) return;
  int nn = idx / K, k = idx - nn*K;
  dstp[idx] = f2us(srcp[(size_t)k*NCc + nn]);
}

// ---------- MFMA GEMM body (R6-verified core): C[n,NC](bf16) = A@W (+bias/addv, relu) ----------
template<int NC, typename AT>
__device__ __forceinline__ void mgemm_body(int bid,
                 const AT* __restrict__ A0, const AT* __restrict__ A1,
                 int lda, const us16* __restrict__ Wt,
                 const float* __restrict__ bias, const float* __restrict__ addv,
                 us16* __restrict__ C, int ldc, int n, int KC, int relu,
                 us16* Alds, us16* Wlds){
  constexpr int NB = NC/16;
  const int tid = threadIdx.x;
  const int lane = tid & 63, wid = tid >> 6;
  const int rowBase = bid*128;
  f32x4 zero = {0.f,0.f,0.f,0.f};
  f32x4 acc[2][NB];
  #pragma unroll
  for(int m=0;m<2;m++)
    #pragma unroll
    for(int nb=0;nb<NB;nb++) acc[m][nb] = zero;

  for(int kk=0; kk<KC; kk+=64){
    const AT* Ab = (kk<128)? A0 : A1;
    const int kc = (kk<128)? kk : (kk-128);
    #pragma unroll
    for(int p=0;p<4;p++){
      int idx = p*256 + tid;
      int r = idx>>3, u = idx&7;
      int row = rowBase + r;
      uint4 v = make_uint4(0u,0u,0u,0u);
      if(row<n){
        if constexpr (sizeof(AT)==2){
          v = *(const uint4*)(Ab + (size_t)row*lda + kc + u*8);
        } else {
          float4 f0 = *(const float4*)(Ab + (size_t)row*lda + kc + u*8);
          float4 f1 = *(const float4*)(Ab + (size_t)row*lda + kc + u*8 + 4);
          us16 tmp[8] = {f2us(f0.x),f2us(f0.y),f2us(f0.z),f2us(f0.w),
                         f2us(f1.x),f2us(f1.y),f2us(f1.z),f2us(f1.w)};
          v = *(const uint4*)tmp;
        }
      }
      *(uint4*)&Alds[(r*8 + (u ^ (r&7)))*8] = v;
    }
    #pragma unroll
    for(int p=0;p<NB/2;p++){
      int idx = p*256 + tid;
      int cI = idx>>3, u = idx&7;
      uint4 v = *(const uint4*)(Wt + (size_t)cI*KC + kk + u*8);
      *(uint4*)&Wlds[(cI*8 + (u ^ (cI&7)))*8] = v;
    }
    __syncthreads();
    #pragma unroll
    for(int ks=0;ks<2;ks++){
      bf16x8 af[2];
      #pragma unroll
      for(int m=0;m<2;m++){
        int r = wid*32 + m*16 + (lane&15);
        int u = (ks*4 + (lane>>4)) ^ (r&7);
        af[m] = *(const bf16x8*)&Alds[(r*8+u)*8];
      }
      #pragma unroll
      for(int nb=0;nb<NB;nb++){
        int c2 = nb*16 + (lane&15);
        int u = (ks*4 + (lane>>4)) ^ (c2&7);
        bf16x8 bfv = *(const bf16x8*)&Wlds[(c2*8+u)*8];
        #pragma unroll
        for(int m=0;m<2;m++)
          acc[m][nb] = __builtin_amdgcn_mfma_f32_16x16x32_bf16(af[m], bfv, acc[m][nb], 0,0,0);
      }
    }
    __syncthreads();
  }
  #pragma unroll
  for(int nb=0;nb<NB;nb++){
    int col = nb*16 + (lane&15);
    float badd = (bias? bias[col]:0.f) + (addv? addv[col]:0.f);
    #pragma unroll
    for(int m=0;m<2;m++){
      #pragma unroll
      for(int j=0;j<4;j++){
        int row = rowBase + wid*32 + m*16 + (lane>>4)*4 + j;
        if(row<n){
          float v = acc[m][nb][j] + badd;
          if(relu) v = fmaxf(v,0.f);
          C[(size_t)row*ldc + col] = f2us(v);
        }
      }
    }
  }
}

// standalone GEMM kernel
template<int NC, typename AT>
__global__ __launch_bounds__(256) void k_mgemm(const AT* __restrict__ A0, const AT* __restrict__ A1,
                 int lda, const us16* __restrict__ Wt,
                 const float* __restrict__ bias, const float* __restrict__ addv,
                 us16* __restrict__ C, int ldc, int n, int KC, int relu){
  __shared__ us16 smem[128*64 + NC*64];
  mgemm_body<NC,AT>(blockIdx.x, A0,A1,lda, Wt, bias,addv, C,ldc, n,KC,relu, smem, smem+128*64);
}

// ---- FUSED: [coef | g00 | g10] (coef = streaming RMW, occupancy-tolerant) ----
__global__ __launch_bounds__(256) void k_coef_l0(
    uint2* __restrict__ csr, const int* __restrict__ rp, const float* __restrict__ disA,
    int E, int EB, int GB,
    const us16* __restrict__ B0,
    const us16* __restrict__ wt_g00, const us16* __restrict__ wt_g10,
    us16* __restrict__ B1, us16* __restrict__ B2, int n){
  __shared__ us16 smem[128*64 + 128*64];
  int b = blockIdx.x;
  if (b < EB){
    int e = b*256 + threadIdx.x;
    if (e < E){
      int rpN = rp[N_NODES];
      int t = (e >= rpN) ? 1 : 0;
      uint2 q = csr[e];
      float w = __uint_as_float(q.y) * disA[t*N_NODES + (int)q.x];
      csr[e] = make_uint2(q.x, __float_as_uint(w));
    }
  } else if (b < EB + GB){
    mgemm_body<128,us16>(b - EB, B0, B0, 128, wt_g00, nullptr, nullptr, B1, 128, n, 128, 0,
                         smem, smem + 128*64);
  } else {
    mgemm_body<128,us16>(b - EB - GB, B0, B0, 128, wt_g10, nullptr, nullptr, B2, 128, n, 128, 0,
                         smem, smem + 128*64);
  }
}

// ---- FUSED: [gemmA | gemmB] (both 128-col, bf16 A) ----
__global__ __launch_bounds__(256) void k_gemm2(int GB,
    const us16* __restrict__ Aa, const us16* __restrict__ Wa, us16* __restrict__ Ca,
    const us16* __restrict__ Ab, const us16* __restrict__ Wb, us16* __restrict__ Cb, int n){
  __shared__ us16 smem[128*64 + 128*64];
  int b = blockIdx.x;
  if (b < GB)
    mgemm_body<128,us16>(b, Aa, Aa, 128, Wa, nullptr, nullptr, Ca, 128, n, 128, 0, smem, smem+128*64);
  else
    mgemm_body<128,us16>(b-GB, Ab, Ab, 128, Wb, nullptr, nullptr, Cb, 128, n, 128, 0, smem, smem+128*64);
}

// ---- p2 GEMM + final dot fused: out[r] = relu(Z1@W2+b2) . w3 + b3  (f32 out) ----
__global__ __launch_bounds__(256) void k_p2out(const us16* __restrict__ Z1,
                 const us16* __restrict__ Wt, const float* __restrict__ b2,
                 const float* __restrict__ w3, const float* __restrict__ b3,
                 float* __restrict__ out, int n){
  __shared__ us16 smem[128*64 + 64*64];
  us16* Alds = smem; us16* Wlds = smem + 128*64;
  const int tid = threadIdx.x;
  const int lane = tid & 63, wid = tid >> 6;
  const int rowBase = blockIdx.x*128;
  f32x4 zero = {0.f,0.f,0.f,0.f};
  f32x4 acc[2][4];
  #pragma unroll
  for(int m=0;m<2;m++)
    #pragma unroll
    for(int nb=0;nb<4;nb++) acc[m][nb] = zero;

  // single K-tile: KC = 64
  {
    #pragma unroll
    for(int p=0;p<4;p++){
      int idx = p*256 + tid;
      int r = idx>>3, u = idx&7;
      int row = rowBase + r;
      uint4 v = make_uint4(0u,0u,0u,0u);
      if(row<n) v = *(const uint4*)(Z1 + (size_t)row*64 + u*8);
      *(uint4*)&Alds[(r*8 + (u ^ (r&7)))*8] = v;
    }
    #pragma unroll
    for(int p=0;p<2;p++){
      int idx = p*256 + tid;
      int cI = idx>>3, u = idx&7;
      uint4 v = *(const uint4*)(Wt + (size_t)cI*64 + u*8);
      *(uint4*)&Wlds[(cI*8 + (u ^ (cI&7)))*8] = v;
    }
    __syncthreads();
    #pragma unroll
    for(int ks=0;ks<2;ks++){
      bf16x8 af[2];
      #pragma unroll
      for(int m=0;m<2;m++){
        int r = wid*32 + m*16 + (lane&15);
        int u = (ks*4 + (lane>>4)) ^ (r&7);
        af[m] = *(const bf16x8*)&Alds[(r*8+u)*8];
      }
      #pragma unroll
      for(int nb=0;nb<4;nb++){
        int c2 = nb*16 + (lane&15);
        int u = (ks*4 + (lane>>4)) ^ (c2&7);
        bf16x8 bfv = *(const bf16x8*)&Wlds[(c2*8+u)*8];
        #pragma unroll
        for(int m=0;m<2;m++)
          acc[m][nb] = __builtin_amdgcn_mfma_f32_16x16x32_bf16(af[m], bfv, acc[m][nb], 0,0,0);
      }
    }
    __syncthreads();
  }
  // epilogue: per-lane dot over its 4 cols, shfl reduce across the 16-lane row group
  float w3f[4], b2f[4];
  #pragma unroll
  for(int nb=0;nb<4;nb++){
    int col = nb*16 + (lane&15);
    w3f[nb] = w3[col];
    b2f[nb] = b2[col];
  }
  float b3v = b3[0];
  #pragma unroll
  for(int m=0;m<2;m++){
    #pragma unroll
    for(int j=0;j<4;j++){
      float p = 0.f;
      #pragma unroll
      for(int nb=0;nb<4;nb++){
        float v = acc[m][nb][j] + b2f[nb];
        v = fmaxf(v, 0.f);
        p += v * w3f[nb];
      }
      p += __shfl_xor(p, 1, 64);
      p += __shfl_xor(p, 2, 64);
      p += __shfl_xor(p, 4, 64);
      p += __shfl_xor(p, 8, 64);
      int row = rowBase + wid*32 + m*16 + (lane>>4)*4 + j;
      if ((lane & 15) == 0 && row < n) out[row] = p + b3v;
    }
  }
}

// --- aggregation body (R15-proven): 4 rows/wave, 16 lanes x uint4 slices, chunk-4 ---
__device__ __forceinline__ void agg_body(int bid, const us16* __restrict__ T,
  const uint2* __restrict__ csr,
  const int* __restrict__ rp, const int* __restrict__ cnt, int rowOfs,
  const float* __restrict__ dis,
  const float* __restrict__ bias, const float* __restrict__ gamma, const float* __restrict__ beta,
  const float* __restrict__ rm, const float* __restrict__ rv,
  const us16* __restrict__ resid,
  us16* __restrict__ out, int relu, int n){
  const int wid = threadIdx.x >> 6, lane = threadIdx.x & 63;
  const int qg = lane >> 4;
  const int sl = lane & 15;
  int r = bid*16 + wid*4 + qg;
  if (r >= n) return;
  const int c0 = sl*8;
  int idx = rowOfs + r;
  int e0 = rp[idx];
  int ec = cnt[idx];
  const uint2* cp = csr + e0;
  float a[8];
  #pragma unroll
  for(int j=0;j<8;j++) a[j]=0.f;
  int nchunk = ec >> 2;
  int rem = ec & 3;
  for(int ch=0; ch<nchunk; ch++){
    uint2 q[4];
    #pragma unroll
    for(int i=0;i<4;i++) q[i] = cp[i];
    cp += 4;
    uint4 v[4];
    #pragma unroll
    for(int i=0;i<4;i++) v[i] = *(const uint4*)(T + (size_t)q[i].x*128 + c0);
    #pragma unroll
    for(int i=0;i<4;i++){
      float c = __uint_as_float(q[i].y);
      a[0] += c*us2f((us16)(v[i].x & 0xffffu));
      a[1] += c*us2f((us16)(v[i].x >> 16));
      a[2] += c*us2f((us16)(v[i].y & 0xffffu));
      a[3] += c*us2f((us16)(v[i].y >> 16));
      a[4] += c*us2f((us16)(v[i].z & 0xffffu));
      a[5] += c*us2f((us16)(v[i].z >> 16));
      a[6] += c*us2f((us16)(v[i].w & 0xffffu));
      a[7] += c*us2f((us16)(v[i].w >> 16));
    }
  }
  for(int i=0;i<rem;i++){
    uint2 q = cp[i];
    float c = __uint_as_float(q.y);
    uint4 v = *(const uint4*)(T + (size_t)q.x*128 + c0);
    a[0] += c*us2f((us16)(v.x & 0xffffu));
    a[1] += c*us2f((us16)(v.x >> 16));
    a[2] += c*us2f((us16)(v.y & 0xffffu));
    a[3] += c*us2f((us16)(v.y >> 16));
    a[4] += c*us2f((us16)(v.z & 0xffffu));
    a[5] += c*us2f((us16)(v.z >> 16));
    a[6] += c*us2f((us16)(v.w & 0xffffu));
    a[7] += c*us2f((us16)(v.w >> 16));
  }
  float disr = dis[r]; float invdeg = disr*disr;
  uint4 vs = *(const uint4*)(T + (size_t)r*128 + c0);
  float s[8] = {
    us2f((us16)(vs.x & 0xffffu)), us2f((us16)(vs.x >> 16)),
    us2f((us16)(vs.y & 0xffffu)), us2f((us16)(vs.y >> 16)),
    us2f((us16)(vs.z & 0xffffu)), us2f((us16)(vs.z >> 16)),
    us2f((us16)(vs.w & 0xffffu)), us2f((us16)(vs.w >> 16))
  };
  float4 bi0 = *(const float4*)(bias + c0);
  float4 bi1 = *(const float4*)(bias + c0 + 4);
  float4 ga0 = *(const float4*)(gamma + c0);
  float4 ga1 = *(const float4*)(gamma + c0 + 4);
  float4 be0 = *(const float4*)(beta + c0);
  float4 be1 = *(const float4*)(beta + c0 + 4);
  float4 rm0 = *(const float4*)(rm + c0);
  float4 rm1 = *(const float4*)(rm + c0 + 4);
  float4 rv0 = *(const float4*)(rv + c0);
  float4 rv1 = *(const float4*)(rv + c0 + 4);
  float bif[8] = {bi0.x,bi0.y,bi0.z,bi0.w,bi1.x,bi1.y,bi1.z,bi1.w};
  float gaf[8] = {ga0.x,ga0.y,ga0.z,ga0.w,ga1.x,ga1.y,ga1.z,ga1.w};
  float bef[8] = {be0.x,be0.y,be0.z,be0.w,be1.x,be1.y,be1.z,be1.w};
  float rmf[8] = {rm0.x,rm0.y,rm0.z,rm0.w,rm1.x,rm1.y,rm1.z,rm1.w};
  float rvf[8] = {rv0.x,rv0.y,rv0.z,rv0.w,rv1.x,rv1.y,rv1.z,rv1.w};
  float o[8];
  #pragma unroll
  for(int j=0;j<8;j++){
    float v = a[j]*disr + s[j]*invdeg + bif[j];
    v = (v - rmf[j])*(gaf[j]*rsqrtf(rvf[j] + 1e-5f)) + bef[j];
    if (relu) v = fmaxf(v,0.f);
    o[j] = v;
  }
  if (resid){
    uint4 vr = *(const uint4*)(resid + (size_t)r*128 + c0);
    o[0] += us2f((us16)(vr.x & 0xffffu));
    o[1] += us2f((us16)(vr.x >> 16));
    o[2] += us2f((us16)(vr.y & 0xffffu));
    o[3] += us2f((us16)(vr.y >> 16));
    o[4] += us2f((us16)(vr.z & 0xffffu));
    o[5] += us2f((us16)(vr.z >> 16));
    o[6] += us2f((us16)(vr.w & 0xffffu));
    o[7] += us2f((us16)(vr.w >> 16));
  }
  uint4 up;
  up.x = (unsigned)f2us(o[0]) | ((unsigned)f2us(o[1]) << 16);
  up.y = (unsigned)f2us(o[2]) | ((unsigned)f2us(o[3]) << 16);
  up.z = (unsigned)f2us(o[4]) | ((unsigned)f2us(o[5]) << 16);
  up.w = (unsigned)f2us(o[6]) | ((unsigned)f2us(o[7]) << 16);
  *(uint4*)(out + (size_t)r*128 + c0) = up;
}

// ---- FUSED: [agg-chain0 | agg-chain1] ----
__global__ __launch_bounds__(256) void k_agg2(int AB,
  const uint2* __restrict__ csr, const int* __restrict__ rp, const int* __restrict__ cnt,
  const float* __restrict__ disA,
  const us16* __restrict__ Ta,
  const float* __restrict__ ba, const float* __restrict__ gaa, const float* __restrict__ bea,
  const float* __restrict__ rma, const float* __restrict__ rva,
  const us16* __restrict__ resida, us16* __restrict__ outa, int relua,
  const us16* __restrict__ Tb,
  const float* __restrict__ bb, const float* __restrict__ gab, const float* __restrict__ beb,
  const float* __restrict__ rmb, const float* __restrict__ rvb,
  const us16* __restrict__ residb, us16* __restrict__ outb, int relub, int n){
  int b = blockIdx.x;
  if (b < AB)
    agg_body(b, Ta, csr, rp, cnt, 0, disA, ba,gaa,bea,rma,rva, resida, outa, relua, n);
  else
    agg_body(b-AB, Tb, csr, rp, cnt, N_NODES, disA+N_NODES, bb,gab,beb,rmb,rvb, residb, outb, relub, n);
}

// ------------- seed constant -------------
__global__ void k_const64(const us16* __restrict__ X0, const us16* __restrict__ X1,
                          const int* __restrict__ seed,
                          const float* __restrict__ pw1, const float* __restrict__ pb1,
                          float* __restrict__ c64){
  int j = threadIdx.x;  // 64 threads
  int s = seed[0];
  const us16* x0 = X0 + (size_t)s*128;
  const us16* x1 = X1 + (size_t)s*128;
  float acc = pb1[j];
  #pragma unroll 8
  for(int k=0;k<128;k++) acc += us2f(x0[k]) * pw1[(256+k)*64 + j];
  #pragma unroll 8
  for(int k=0;k<128;k++) acc += us2f(x1[k]) * pw1[(384+k)*64 + j];
  c64[j]=acc;
}

extern "C" void kernel_launch(void* const* d_in, const int* in_sizes, int n_in,
                              void* d_out, int out_size, void* d_ws, size_t ws_size,
                              hipStream_t stream){
  const int N = N_NODES;
  const int E = in_sizes[2];
  const float* x   = (const float*)d_in[0];
  const int*   ei  = (const int*)d_in[1];
  const int*   et  = (const int*)d_in[2];
  const float* ew  = (const float*)d_in[3];
  const int*   seed= (const int*)d_in[4];
  const float* ft_w= (const float*)d_in[5];
  const float* ft_b= (const float*)d_in[6];
  const float* g0_w= (const float*)d_in[7];
  const float* g0_b= (const float*)d_in[8];
  const float* g0_g= (const float*)d_in[9];
  const float* g0_be=(const float*)d_in[10];
  const float* g0_rm=(const float*)d_in[11];
  const float* g0_rv=(const float*)d_in[12];
  const float* g1_w= (const float*)d_in[13];
  const float* g1_b= (const float*)d_in[14];
  const float* g1_g= (const float*)d_in[15];
  const float* g1_be=(const float*)d_in[16];
  const float* g1_rm=(const float*)d_in[17];
  const float* g1_rv=(const float*)d_in[18];
  const float* p_w1= (const float*)d_in[19];
  const float* p_b1= (const float*)d_in[20];
  const float* p_w2= (const float*)d_in[21];
  const float* p_b2= (const float*)d_in[22];
  const float* p_w3= (const float*)d_in[23];
  const float* p_b3= (const float*)d_in[24];
  float* out = (float*)d_out;

  // Footprint ~117.8 MB (< proven 119.2 MB). eofs aliases B3 (first feature write to B3 is h1, after fill).
  char* wsp = (char*)d_ws;
  auto alloc = [&](size_t bytes)->char*{ char* p = wsp; wsp += (bytes + 255) & ~(size_t)255; return p; };
  us16* B0 = (us16*)alloc((size_t)N*128*2);
  us16* B1 = (us16*)alloc((size_t)N*128*2);
  us16* B2 = (us16*)alloc((size_t)N*128*2);
  us16* B3 = (us16*)alloc((size_t)N*128*2);
  uint2* csr = (uint2*)alloc((size_t)E*8);
  float* disA=(float*)alloc((size_t)2*N*4);
  int* cnt =(int*)alloc((size_t)2*N*4);
  int* rp  =(int*)alloc((size_t)2*N*4);
  int* bsum=(int*)alloc(4096);
  float* c64=(float*)alloc(256);
  us16* wt =(us16*)alloc((size_t)102400*2);
  int* eofs = (int*)B3;
  us16* Z1 = B1;                 // free after x0/x1 land in B0/B3

  const int* srcp = ei;
  const int* dstp = ei + E;

  int M = 2*N;
  int CB = (E+255)/256;
  int GB = (N+127)/128;
  int AB = (N+15)/16;
  int SB = (M+2047)/2048;

  // ---- prep ----
  k_init<<<(M+255)/256,256,0,stream>>>(cnt,M);
  dim3 pg(64,7);
  k_prepw<<<pg,256,0,stream>>>(ft_w,g0_w,g1_w,p_w1,p_w2,wt);

  const us16* wt_ft = wt;
  const us16* wt_g00= wt+16384;
  const us16* wt_g01= wt+32768;
  const us16* wt_g10= wt+49152;
  const us16* wt_g11= wt+65536;
  const us16* wt_p1 = wt+81920;
  const us16* wt_p2 = wt+98304;

  // ---- feature transform (standalone, full occupancy for subsequent atomics) ----
  k_mgemm<128,float><<<GB,256,0,stream>>>(x,x,128, wt_ft, ft_b, nullptr, B0,128, N,128,1);
  // ---- graph build (all standalone at native occupancy) ----
  k_cnt<<<CB,256,0,stream>>>(dstp,et,cnt,eofs,E);
  k_scan_reduce<<<SB,256,0,stream>>>(cnt,bsum,M);
  k_scan_top<<<1,64,0,stream>>>(bsum,SB);
  k_scan_apply<<<SB,256,0,stream>>>(cnt,bsum,rp,M);
  k_edge_fill<<<CB,256,0,stream>>>(srcp,dstp,et,ew,rp,eofs,csr,E);
  k_deg_csr<<<(M+255)/256,256,0,stream>>>(csr,rp,cnt,disA,M);
  // ---- fused [coef | g00 | g10] ----
  k_coef_l0<<<CB+2*GB,256,0,stream>>>(csr,rp,disA,E,CB,GB, B0,wt_g00,wt_g10,B1,B2,N);

  // ---- parallel chains ----
  // stage 1: [agg0: B1 -> B0 (h0) | agg1: B2 -> B3 (h1)]
  k_agg2<<<2*AB,256,0,stream>>>(AB, csr,rp,cnt,disA,
      B1, g0_b,g0_g,g0_be,g0_rm,g0_rv, nullptr, B0, 1,
      B2, g1_b,g1_g,g1_be,g1_rm,g1_rv, nullptr, B3, 1, N);
  // stage 2: [g01: B0 -> B1 | g11: B3 -> B2]
  k_gemm2<<<2*GB,256,0,stream>>>(GB, B0,wt_g01,B1, B3,wt_g11,B2, N);
  // stage 3: [agg0b: B1 + resid B0 -> B0 (x0) | agg1b: B2 + resid B3 -> B3 (x1)]
  k_agg2<<<2*AB,256,0,stream>>>(AB, csr,rp,cnt,disA,
      B1, g0_b+128,g0_g+128,g0_be+128,g0_rm+128,g0_rv+128, B0, B0, 0,
      B2, g1_b+128,g1_g+128,g1_be+128,g1_rm+128,g1_rv+128, B3, B3, 0, N);

  // ---- predictor: x0=B0, x1=B3 ----
  k_const64<<<1,64,0,stream>>>(B0,B3,seed,p_w1,p_b1,c64);
  k_mgemm<64,us16><<<GB,256,0,stream>>>(B0,B3,128, wt_p1, nullptr, c64, Z1,64, N,256,1);
  k_p2out<<<GB,256,0,stream>>>(Z1, wt_p2, p_b2, p_w3, p_b3, out, N);
}